// Round 2
// baseline (1224.869 us; speedup 1.0000x reference)
//
#include <hip/hip_runtime.h>
#include <stdint.h>
#include <stddef.h>

#define NROWS 32768
#define KCODES 8192
#define DIM 512

/* ---- filter GEMM (8-phase 256^2 pipeline, compile-time double buffer) ---- */
#define BMG 256
#define BNG 256
#define BKG 64
#define KSPLIT 2
#define SEGC (KCODES / KSPLIT)           /* 4096 */
#define NKT (SEGC / BNG)                 /* 16 column tiles per block */
#define NGITER (NKT * (DIM / (2 * BKG))) /* 64 iterations (2 K-tiles each) */
#define NGK (NKT * (DIM / BKG))          /* 128 global K-tiles per block */
#define TAU 1.5e-3f
#define MAXC 64
#define CHAINSPLIT 384 /* OpenBLAS sgemm kc */

typedef __attribute__((ext_vector_type(8))) short short8;
typedef __attribute__((ext_vector_type(4))) float floatx4;
typedef unsigned long long ull;

static __device__ __forceinline__ unsigned short f2bf(float f) {
  unsigned u = __float_as_uint(f);
  unsigned r = (u + 0x7FFFu + ((u >> 16) & 1u)) >> 16;
  return (unsigned short)r;
}
// monotone float->uint key (order-preserving for finite floats)
static __device__ __forceinline__ unsigned fkey(float s) {
  unsigned b = __float_as_uint(s);
  return b ^ (((int)b < 0) ? 0xFFFFFFFFu : 0x80000000u);
}

#define GLDS16(g, l)                                                        \
  __builtin_amdgcn_global_load_lds(                                         \
      (const __attribute__((address_space(1))) unsigned int*)(g),           \
      (__attribute__((address_space(3))) unsigned int*)(l), 16, 0, 0)

// ---------------------------------------------------------------------------
// numpy-exact row norm (unchanged).
// ---------------------------------------------------------------------------
__global__ __launch_bounds__(256) void k_rownorm(const float* __restrict__ x,
                                                 float* __restrict__ nout,
                                                 int nrows,
                                                 int* __restrict__ counts,
                                                 int ninit,
                                                 float* __restrict__ lossacc) {
  const int tid = threadIdx.x;
  const int j = tid & 7;
  const int row = blockIdx.x * 32 + (tid >> 3);
  if (counts != nullptr && j == 0 && row < ninit) counts[row] = 0;
  if (lossacc != nullptr && blockIdx.x == 0 && tid == 0) *lossacc = 0.0f;
  if (row >= nrows) return;
  const float* xr = x + (size_t)row * DIM;
  float blk[4];
#pragma unroll
  for (int b = 0; b < 4; ++b) {
    const float* p = xr + b * 128;
    float r = __fmul_rn(p[j], p[j]);
    for (int i = 8; i < 128; i += 8) {
      const float t = p[i + j];
      r = __fadd_rn(r, __fmul_rn(t, t));
    }
    r = __fadd_rn(r, __shfl_xor(r, 1, 64));
    r = __fadd_rn(r, __shfl_xor(r, 2, 64));
    r = __fadd_rn(r, __shfl_xor(r, 4, 64));
    blk[b] = r;
  }
  const float tot =
      __fadd_rn(__fadd_rn(blk[0], blk[1]), __fadd_rn(blk[2], blk[3]));
  if (j == 0) nout[row] = fmaxf(__fsqrt_rn(tot), 1e-12f);
}

// ---------------------------------------------------------------------------
// Normalized rows (unchanged).
// ---------------------------------------------------------------------------
__global__ __launch_bounds__(256) void k_normstore(const float* __restrict__ x,
                                                   const float* __restrict__ nin,
                                                   unsigned short* __restrict__ xb,
                                                   float* __restrict__ xf) {
  const int wv = threadIdx.x >> 6;
  const int lane = threadIdx.x & 63;
  const int row = blockIdx.x * 4 + wv;
  const float n = nin[row];
  const float4* xr = (const float4*)(x + (size_t)row * DIM);
#pragma unroll
  for (int h = 0; h < 2; ++h) {
    const float4 v = xr[lane + 64 * h];
    const float q0 = __fdiv_rn(v.x, n);
    const float q1 = __fdiv_rn(v.y, n);
    const float q2 = __fdiv_rn(v.z, n);
    const float q3 = __fdiv_rn(v.w, n);
    if (xf != nullptr)
      ((float4*)(xf + (size_t)row * DIM))[lane + 64 * h] =
          make_float4(q0, q1, q2, q3);
    *(ushort4*)(xb + (size_t)row * DIM + 256 * h + 4 * lane) =
        make_ushort4(f2bf(q0), f2bf(q1), f2bf(q2), f2bf(q3));
  }
}

// ---------------------------------------------------------------------------
// bf16 MFMA filter GEMM, 8-phase 256x256 pipeline with COMPILE-TIME double
// buffering: four distinct __shared__ arrays (As0/Bs0/As1/Bs1, 32KB each) so
// LLVM alias analysis can prove the next-tile global_load_lds writes are
// disjoint from the current-tile ds_reads -> no conservative vmcnt(0) before
// each phase's LDS reads (round-1's suspected serializer). Reads are issued
// before the stage within q0; the only vm waits are the explicit vmcnt(0) at
// q3/q7 (cross-wave LDS visibility, before the barrier that publishes the
// newly staged tile). lgkm waits are left to the compiler (fine-grained,
// interleaved with MFMAs). Slot-reuse safety: every ds_read is consumed by
// the same phase's MFMAs (compiler lgkm drain) before the following barrier,
// and a buffer is only re-staged >=2 barriers after its last read.
// Grid: (128, KSPLIT=2) = 256 blocks = 1/CU; bijective XCD swizzle maps each
// XCD to one 4MB cnb segment. Collect epilogue per 256-col tile (unchanged).
// ---------------------------------------------------------------------------
__global__ __launch_bounds__(512, 2) void k_gemm_collect(
    const unsigned short* __restrict__ znb, const unsigned short* __restrict__ cnb,
    int* __restrict__ counts, int* __restrict__ cands) {
  __shared__ __align__(16) short As0[BMG * BKG]; /* 32KB */
  __shared__ __align__(16) short Bs0[BNG * BKG]; /* 32KB */
  __shared__ __align__(16) short As1[BMG * BKG]; /* 32KB */
  __shared__ __align__(16) short Bs1[BNG * BKG]; /* 32KB */
  __shared__ __align__(16) float redm[256][4];   /* per-wave row maxes */
  __shared__ float runm[256];                    /* running row max */

  const int tid = threadIdx.x;
  const int lane = tid & 63;
  const int w = tid >> 6; /* wave 0..7 */
  const int wr = w >> 2;  /* M half: rows wr*128.. */
  const int wc = w & 3;   /* N quarter: cols wc*64.. */
  const int l15 = lane & 15;
  const int l4 = lane >> 4;

  /* XCD-aware bijective swizzle: 256 blocks -> 32 contiguous per XCD */
  const int bid = blockIdx.y * (NROWS / BMG) + blockIdx.x;
  const int logical = (bid & 7) * 32 + (bid >> 3);
  const int row0 = (logical & (NROWS / BMG - 1)) * BMG;
  const int seg0 = (logical >> 7) * SEGC;

  /* stage one 256x64 A tile + one 256x64 B tile into the given arrays.
     granule-XOR swizzle via pre-swizzled global source (T2-equivalent). */
  auto stage = [&](short* Ad, short* Bd, int gk) {
    if (gk >= NGK) gk -= 2; /* tail: idempotent re-stage */
    const int d0 = (gk & 7) * BKG;
    const int cb0 = seg0 + (gk >> 3) * BNG;
#pragma unroll
    for (int l = 0; l < 4; ++l) {
      const int g = (l * 8 + w) * 64 + lane; /* granule id 0..2047 */
      const int r = g >> 3;                  /* tile row 0..255 */
      const int cg = (g & 7) ^ (r & 7);      /* pre-swizzled source granule */
      GLDS16(znb + (size_t)(row0 + r) * DIM + d0 + cg * 8,
             Ad + (l * 8 + w) * 512);
      GLDS16(cnb + (size_t)(cb0 + r) * DIM + d0 + cg * 8,
             Bd + (l * 8 + w) * 512);
    }
  };

  for (int x = tid; x < 256; x += 512) runm[x] = -2.0f;

  floatx4 acc[8][4];
#pragma unroll
  for (int i = 0; i < 8; ++i)
#pragma unroll
    for (int n = 0; n < 4; ++n) {
      floatx4 zz = {0.f, 0.f, 0.f, 0.f};
      acc[i][n] = zz;
    }

  short8 bf[4][2]; /* B frags held across the 4 phases of a K-tile */

  /* one K-tile: 4 phases {reads, (q0: stage next), bar, MFMA, (q3: vmcnt0), bar} */
  auto compute_half = [&](const short* Ac, const short* Bc, short* An,
                          short* Bn, int gknext) {
#pragma unroll
    for (int q = 0; q < 4; ++q) {
      if (q == 0) {
#pragma unroll
        for (int n = 0; n < 4; ++n)
#pragma unroll
          for (int k2 = 0; k2 < 2; ++k2) {
            const int rb = wc * 64 + n * 16 + l15;
            bf[n][k2] =
                *(const short8*)&Bc[rb * 64 + (((l4 + k2 * 4) ^ (rb & 7)) << 3)];
          }
      }
      short8 af[2][2];
#pragma unroll
      for (int ii = 0; ii < 2; ++ii)
#pragma unroll
        for (int k2 = 0; k2 < 2; ++k2) {
          const int ra = wr * 128 + (2 * q + ii) * 16 + l15;
          af[ii][k2] =
              *(const short8*)&Ac[ra * 64 + (((l4 + k2 * 4) ^ (ra & 7)) << 3)];
        }
      if (q == 0) stage(An, Bn, gknext); /* issue AFTER reads, overlaps MFMA */
      __builtin_amdgcn_s_barrier();
      __builtin_amdgcn_s_setprio(1);
#pragma unroll
      for (int ii = 0; ii < 2; ++ii)
#pragma unroll
        for (int n = 0; n < 4; ++n)
#pragma unroll
          for (int k2 = 0; k2 < 2; ++k2)
            acc[2 * q + ii][n] = __builtin_amdgcn_mfma_f32_16x16x32_bf16(
                af[ii][k2], bf[n][k2], acc[2 * q + ii][n], 0, 0, 0);
      __builtin_amdgcn_s_setprio(0);
      if (q == 3) asm volatile("s_waitcnt vmcnt(0)" ::: "memory");
      __builtin_amdgcn_s_barrier();
    }
  };

  /* prologue: K-tile 0 into As0/Bs0 */
  stage(As0, Bs0, 0);
  asm volatile("s_waitcnt vmcnt(0)" ::: "memory");
  __builtin_amdgcn_s_barrier();

  for (int giter = 0; giter < NGITER; ++giter) {
    compute_half(As0, Bs0, As1, Bs1, 2 * giter + 1); /* even tile */
    compute_half(As1, Bs1, As0, Bs0, 2 * giter + 2); /* odd tile */

    /* ---- per-column-tile collect epilogue (every 4 iterations) ---- */
    if ((giter & 3) == 3) {
      const int col0 = seg0 + (giter >> 2) * BNG;
      /* step A: wave-local per-row max over this wave's 64 cols */
#pragma unroll
      for (int i = 0; i < 8; ++i)
#pragma unroll
        for (int r = 0; r < 4; ++r) {
          float v = fmaxf(fmaxf(acc[i][0][r], acc[i][1][r]),
                          fmaxf(acc[i][2][r], acc[i][3][r]));
#pragma unroll
          for (int off = 1; off < 16; off <<= 1)
            v = fmaxf(v, __shfl_xor(v, off, 64));
          if (l15 == 0) redm[wr * 128 + i * 16 + l4 * 4 + r][wc] = v;
        }
      __syncthreads();
      /* step B: cross-wave max + threshold + collect (reads old runm) */
#pragma unroll
      for (int i = 0; i < 8; ++i)
#pragma unroll
        for (int r = 0; r < 4; ++r) {
          const int rowt = wr * 128 + i * 16 + l4 * 4 + r;
          const float4 m4 = *(const float4*)redm[rowt];
          const float nm = fmaxf(
              runm[rowt], fmaxf(fmaxf(m4.x, m4.y), fmaxf(m4.z, m4.w)));
          const float th = nm - TAU;
          const int rowg = row0 + rowt;
#pragma unroll
          for (int n = 0; n < 4; ++n) {
            if (acc[i][n][r] >= th) {
              const int slot = atomicAdd(&counts[rowg], 1);
              if (slot < MAXC)
                cands[rowg * MAXC + slot] = col0 + wc * 64 + n * 16 + l15;
            }
          }
#pragma unroll
          for (int n = 0; n < 4; ++n) acc[i][n][r] = 0.f;
        }
      __syncthreads();
      /* step C: designated lanes update running max */
      if (wc == 0 && l15 == 0) {
#pragma unroll
        for (int i = 0; i < 8; ++i)
#pragma unroll
          for (int r = 0; r < 4; ++r) {
            const int rowt = wr * 128 + i * 16 + l4 * 4 + r;
            const float4 m4 = *(const float4*)redm[rowt];
            runm[rowt] = fmaxf(
                runm[rowt], fmaxf(fmaxf(m4.x, m4.y), fmaxf(m4.z, m4.w)));
          }
      }
    }
  }
}

// ---------------------------------------------------------------------------
// fp32-EMULATED rescore (unchanged).
// ---------------------------------------------------------------------------
__global__ __launch_bounds__(256) void k_rescore(
    const float* __restrict__ z, const float* __restrict__ normz,
    const float* __restrict__ cnf, const int* __restrict__ counts,
    const int* __restrict__ cands, int* __restrict__ bestk) {
  __shared__ float zn[4][DIM];
  const int wv = threadIdx.x >> 6;
  const int lane = threadIdx.x & 63;
  const int row = blockIdx.x * 4 + wv;
  const float n = normz[row];
  const float* zr = z + (size_t)row * DIM;
#pragma unroll
  for (int j = 0; j < 8; ++j) {
    const int d = lane * 8 + j;
    zn[wv][d] = __fdiv_rn(zr[d], n);
  }
  __syncthreads();
  const int cnt = counts[row];
  const bool fullscan = (cnt <= 0) || (cnt > MAXC);
  ull best = 0ull;
  if (!fullscan) {
    const int idx = (lane < cnt) ? lane : (cnt - 1);
    const int k = cands[row * MAXC + idx] & (KCODES - 1);
    const float* cr = cnf + (size_t)k * DIM;
    float a1 = 0.f, a2 = 0.f;
    for (int d = 0; d < CHAINSPLIT; d += 4) {
      const float4 c = *(const float4*)(cr + d);
      a1 = fmaf(zn[wv][d], c.x, a1);
      a1 = fmaf(zn[wv][d + 1], c.y, a1);
      a1 = fmaf(zn[wv][d + 2], c.z, a1);
      a1 = fmaf(zn[wv][d + 3], c.w, a1);
    }
    for (int d = CHAINSPLIT; d < DIM; d += 4) {
      const float4 c = *(const float4*)(cr + d);
      a2 = fmaf(zn[wv][d], c.x, a2);
      a2 = fmaf(zn[wv][d + 1], c.y, a2);
      a2 = fmaf(zn[wv][d + 2], c.z, a2);
      a2 = fmaf(zn[wv][d + 3], c.w, a2);
    }
    const float s = __fadd_rn(a1, a2);
    if (lane < cnt) best = ((ull)fkey(s) << 32) | (ull)(8191 - k);
  } else {
    for (int base = 0; base < KCODES; base += 64) {
      const int k = base + lane;
      const float* cr = cnf + (size_t)k * DIM;
      float a1 = 0.f, a2 = 0.f;
      for (int d = 0; d < CHAINSPLIT; d += 4) {
        const float4 c = *(const float4*)(cr + d);
        a1 = fmaf(zn[wv][d], c.x, a1);
        a1 = fmaf(zn[wv][d + 1], c.y, a1);
        a1 = fmaf(zn[wv][d + 2], c.z, a1);
        a1 = fmaf(zn[wv][d + 3], c.w, a1);
      }
      for (int d = CHAINSPLIT; d < DIM; d += 4) {
        const float4 c = *(const float4*)(cr + d);
        a2 = fmaf(zn[wv][d], c.x, a2);
        a2 = fmaf(zn[wv][d + 1], c.y, a2);
        a2 = fmaf(zn[wv][d + 2], c.z, a2);
        a2 = fmaf(zn[wv][d + 3], c.w, a2);
      }
      const float s = __fadd_rn(a1, a2);
      const ull q = ((ull)fkey(s) << 32) | (ull)(8191 - k);
      best = (q > best) ? q : best;
    }
  }
#pragma unroll
  for (int off = 1; off < 64; off <<= 1) {
    const ull o = __shfl_xor(best, off, 64);
    best = (o > best) ? o : best;
  }
  if (lane == 0) bestk[row] = 8191 - (int)(best & 0xFFFFFFFFull);
}

// ---------------------------------------------------------------------------
// Output (unchanged).
// ---------------------------------------------------------------------------
__global__ __launch_bounds__(256) void k_output(
    const float* __restrict__ z, const float* __restrict__ normz,
    const float* __restrict__ cnf, const int* __restrict__ bestk,
    float* __restrict__ out, float* __restrict__ lossacc) {
  const int wv = threadIdx.x >> 6;
  const int lane = threadIdx.x & 63;
  const int row = blockIdx.x * 4 + wv;
  const int k = bestk[row];
  const float n = normz[row];
  const float4* cr = (const float4*)(cnf + (size_t)k * DIM);
  const float4* zr = (const float4*)(z + (size_t)row * DIM);
  float ss = 0.0f;
  float4* orow = (float4*)(out + (size_t)row * DIM);
#pragma unroll
  for (int h = 0; h < 2; ++h) {
    const float4 q = cr[lane + 64 * h];
    const float4 zv = zr[lane + 64 * h];
    orow[lane + 64 * h] = q;
    const float d0 = q.x - __fdiv_rn(zv.x, n);
    const float d1 = q.y - __fdiv_rn(zv.y, n);
    const float d2 = q.z - __fdiv_rn(zv.z, n);
    const float d3 = q.w - __fdiv_rn(zv.w, n);
    ss += d0 * d0 + d1 * d1 + d2 * d2 + d3 * d3;
  }
#pragma unroll
  for (int off = 1; off < 64; off <<= 1) ss += __shfl_xor(ss, off, 64);
  if (lane == 0) {
    atomicAdd(lossacc, ss);
    out[(size_t)NROWS * DIM + row] = (float)k;
  }
}

__global__ void k_loss_final(const float* __restrict__ lossacc,
                             float* __restrict__ out) {
  if (threadIdx.x == 0 && blockIdx.x == 0)
    out[(size_t)NROWS * DIM + NROWS] =
        1.5f * (*lossacc) / (float)((size_t)NROWS * DIM);
}

// ---------------------------------------------------------------------------
extern "C" void kernel_launch(void* const* d_in, const int* in_sizes, int n_in,
                              void* d_out, int out_size, void* d_ws, size_t ws_size,
                              hipStream_t stream) {
  const float* z = (const float*)d_in[0];
  const float* cb = (const float*)d_in[1];
  char* ws = (char*)d_ws;
  // workspace layout, ~64.5 MB total
  float* normz = (float*)(ws);                             // 131072
  float* normc = (float*)(ws + 131072);                    // 32768
  int* counts = (int*)(ws + 163840);                       // 131072
  int* bestk = (int*)(ws + 294912);                        // 131072
  float* lossacc = (float*)(ws + 425984);                  // 4 (padded)
  int* cands = (int*)(ws + 458752);                        // 8388608
  unsigned short* znb = (unsigned short*)(ws + 8847360);   // 33554432
  unsigned short* cnb = (unsigned short*)(ws + 42401792);  // 8388608
  float* cnf = (float*)(ws + 50790400);                    // 16777216
  float* out = (float*)d_out;

  k_rownorm<<<dim3(NROWS / 32), dim3(256), 0, stream>>>(z, normz, NROWS, counts,
                                                        NROWS, lossacc);
  k_rownorm<<<dim3(KCODES / 32), dim3(256), 0, stream>>>(cb, normc, KCODES,
                                                         (int*)nullptr, 0,
                                                         (float*)nullptr);
  k_normstore<<<dim3(NROWS / 4), dim3(256), 0, stream>>>(z, normz, znb,
                                                         (float*)nullptr);
  k_normstore<<<dim3(KCODES / 4), dim3(256), 0, stream>>>(cb, normc, cnb, cnf);
  k_gemm_collect<<<dim3(NROWS / BMG, KSPLIT), dim3(512), 0, stream>>>(znb, cnb,
                                                                      counts, cands);
  k_rescore<<<dim3(NROWS / 4), dim3(256), 0, stream>>>(z, normz, cnf, counts,
                                                       cands, bestk);
  k_output<<<dim3(NROWS / 4), dim3(256), 0, stream>>>(z, normz, cnf, bestk, out,
                                                      lossacc);
  k_loss_final<<<dim3(1), dim3(64), 0, stream>>>(lossacc, out);
}

// Round 3
// 1207.795 us; speedup vs baseline: 1.0141x; 1.0141x over previous
//
#include <hip/hip_runtime.h>
#include <stdint.h>
#include <stddef.h>

#define NROWS 32768
#define KCODES 8192
#define DIM 512

/* ---- filter GEMM: 256^2 tile, 1 barrier + 1 vmcnt(0) per BK=64 K-tile ---- */
#define BMG 256
#define BNG 256
#define BKG 64
#define KSPLIT 2
#define SEGC (KCODES / KSPLIT) /* 4096 */
#define NGK ((SEGC / BNG) * (DIM / BKG)) /* 128 K-tiles per block */
#define TAU 1.5e-3f
#define MAXC 64
#define CHAINSPLIT 384 /* OpenBLAS sgemm kc */

typedef __attribute__((ext_vector_type(8))) short short8;
typedef __attribute__((ext_vector_type(4))) float floatx4;
typedef unsigned long long ull;

static __device__ __forceinline__ unsigned short f2bf(float f) {
  unsigned u = __float_as_uint(f);
  unsigned r = (u + 0x7FFFu + ((u >> 16) & 1u)) >> 16;
  return (unsigned short)r;
}
// monotone float->uint key (order-preserving for finite floats)
static __device__ __forceinline__ unsigned fkey(float s) {
  unsigned b = __float_as_uint(s);
  return b ^ (((int)b < 0) ? 0xFFFFFFFFu : 0x80000000u);
}

#define GLDS16(g, l)                                                        \
  __builtin_amdgcn_global_load_lds(                                         \
      (const __attribute__((address_space(1))) unsigned int*)(g),           \
      (__attribute__((address_space(3))) unsigned int*)(l), 16, 0, 0)

// ---------------------------------------------------------------------------
// numpy-exact row norm, z and codebook fused into one dispatch.
// Math is bit-identical to the previously validated version.
// ---------------------------------------------------------------------------
__global__ __launch_bounds__(256) void k_rownorm2(
    const float* __restrict__ z, const float* __restrict__ cb,
    float* __restrict__ normz, float* __restrict__ normc,
    int* __restrict__ counts, float* __restrict__ lossacc) {
  const int tid = threadIdx.x;
  const int j = tid & 7;
  const int b = blockIdx.x;
  const bool isz = (b < NROWS / 32);
  const float* x = isz ? z : cb;
  float* nout = isz ? normz : normc;
  const int row = (isz ? b : (b - NROWS / 32)) * 32 + (tid >> 3);
  if (isz && j == 0) counts[row] = 0;
  if (b == 0 && tid == 0) *lossacc = 0.0f;
  const float* xr = x + (size_t)row * DIM;
  float blk[4];
#pragma unroll
  for (int bb = 0; bb < 4; ++bb) {
    const float* p = xr + bb * 128;
    float r = __fmul_rn(p[j], p[j]);
    for (int i = 8; i < 128; i += 8) {
      const float t = p[i + j];
      r = __fadd_rn(r, __fmul_rn(t, t));
    }
    r = __fadd_rn(r, __shfl_xor(r, 1, 64));
    r = __fadd_rn(r, __shfl_xor(r, 2, 64));
    r = __fadd_rn(r, __shfl_xor(r, 4, 64));
    blk[bb] = r;
  }
  const float tot =
      __fadd_rn(__fadd_rn(blk[0], blk[1]), __fadd_rn(blk[2], blk[3]));
  if (j == 0) nout[row] = fmaxf(__fsqrt_rn(tot), 1e-12f);
}

// ---------------------------------------------------------------------------
// Normalized rows, z and codebook fused. Bit-identical math.
// ---------------------------------------------------------------------------
__global__ __launch_bounds__(256) void k_normstore2(
    const float* __restrict__ z, const float* __restrict__ cb,
    const float* __restrict__ normz, const float* __restrict__ normc,
    unsigned short* __restrict__ znb, unsigned short* __restrict__ cnb,
    float* __restrict__ cnf) {
  const int wv = threadIdx.x >> 6;
  const int lane = threadIdx.x & 63;
  const int b = blockIdx.x;
  const bool isz = (b < NROWS / 4);
  const int row = (isz ? b : (b - NROWS / 4)) * 4 + wv;
  const float* x = isz ? z : cb;
  const float n = (isz ? normz : normc)[row];
  unsigned short* xb = isz ? znb : cnb;
  float* xf = isz ? (float*)nullptr : cnf;
  const float4* xr = (const float4*)(x + (size_t)row * DIM);
#pragma unroll
  for (int h = 0; h < 2; ++h) {
    const float4 v = xr[lane + 64 * h];
    const float q0 = __fdiv_rn(v.x, n);
    const float q1 = __fdiv_rn(v.y, n);
    const float q2 = __fdiv_rn(v.z, n);
    const float q3 = __fdiv_rn(v.w, n);
    if (xf != nullptr)
      ((float4*)(xf + (size_t)row * DIM))[lane + 64 * h] =
          make_float4(q0, q1, q2, q3);
    *(ushort4*)(xb + (size_t)row * DIM + 256 * h + 4 * lane) =
        make_ushort4(f2bf(q0), f2bf(q1), f2bf(q2), f2bf(q3));
  }
}

// ---------------------------------------------------------------------------
// bf16 MFMA filter GEMM: 256x256 tile, double-buffered LDS, and exactly ONE
// barrier + ONE vmcnt(0) drain per BK=64 K-tile (64 MFMA/wave per barrier --
// 4x fewer drains per MFMA than every previous structure, which all ran at
// the same 513us with matching drain density). Stage of tile t+1 issues
// immediately after the barrier publishing tile t, giving it ~2500 cyc of
// MFMA cover before its drain. No setprio (hurts lockstep GEMM, m190).
// Slot safety: all ds_reads of a buffer complete before the consuming MFMAs
// (compiler lgkm waits) which precede the next barrier in program order; a
// buffer is only re-staged after that barrier. Granule-XOR LDS swizzle via
// pre-swizzled global source (conflict-free, verified 0 in counters).
// Grid: (128, KSPLIT=2) = 256 blocks = 1/CU; bijective XCD swizzle maps each
// XCD to one 4MB cnb segment. Collect epilogue per 256-col tile (every 8 gk).
// ---------------------------------------------------------------------------
__global__ __launch_bounds__(512, 2) void k_gemm_collect(
    const unsigned short* __restrict__ znb, const unsigned short* __restrict__ cnb,
    int* __restrict__ counts, int* __restrict__ cands) {
  __shared__ __align__(16) short As0[BMG * BKG]; /* 32KB */
  __shared__ __align__(16) short Bs0[BNG * BKG]; /* 32KB */
  __shared__ __align__(16) short As1[BMG * BKG]; /* 32KB */
  __shared__ __align__(16) short Bs1[BNG * BKG]; /* 32KB */
  __shared__ __align__(16) float redm[256][4];
  __shared__ float runm[256];

  const int tid = threadIdx.x;
  const int lane = tid & 63;
  const int w = tid >> 6; /* wave 0..7 */
  const int wr = w >> 2;  /* M half: rows wr*128.. */
  const int wc = w & 3;   /* N quarter: cols wc*64.. */
  const int l15 = lane & 15;
  const int l4 = lane >> 4;

  /* XCD-aware bijective swizzle: 256 blocks -> 32 contiguous per XCD */
  const int bid = blockIdx.y * (NROWS / BMG) + blockIdx.x;
  const int logical = (bid & 7) * 32 + (bid >> 3);
  const int row0 = (logical & (NROWS / BMG - 1)) * BMG;
  const int seg0 = (logical >> 7) * SEGC;

  /* per-lane loop-invariant staging geometry (shorts) */
  int aoff[4], boff[4], loff[4];
#pragma unroll
  for (int l = 0; l < 4; ++l) {
    const int g = (l * 8 + w) * 64 + lane; /* granule id 0..2047 */
    const int r = g >> 3;                  /* tile row 0..255 */
    const int cg = (g & 7) ^ (r & 7);      /* pre-swizzled source granule */
    aoff[l] = (row0 + r) * DIM + cg * 8;
    boff[l] = r * DIM + cg * 8;
    loff[l] = (l * 8 + w) * 512;
  }

  auto stage = [&](short* Ad, short* Bd, int gk) {
    if (gk >= NGK) gk = NGK - 2; /* tail: idempotent re-stage of dead buffer */
    const int d0 = (gk & 7) * BKG;
    const size_t cb0 = (size_t)(seg0 + (gk >> 3) * BNG) * DIM;
#pragma unroll
    for (int l = 0; l < 4; ++l) {
      GLDS16(znb + (size_t)aoff[l] + d0, Ad + loff[l]);
      GLDS16(cnb + cb0 + boff[l] + d0, Bd + loff[l]);
    }
  };

  for (int x = tid; x < 256; x += 512) runm[x] = -2.0f;

  floatx4 acc[8][4];
#pragma unroll
  for (int i = 0; i < 8; ++i)
#pragma unroll
    for (int n = 0; n < 4; ++n) {
      floatx4 zz = {0.f, 0.f, 0.f, 0.f};
      acc[i][n] = zz;
    }

  /* full K-tile compute: 8 bf reads + 16 af reads + 64 MFMA, no barriers */
  auto compute = [&](const short* Ac, const short* Bc) {
    short8 bfr[4][2];
#pragma unroll
    for (int n = 0; n < 4; ++n)
#pragma unroll
      for (int k2 = 0; k2 < 2; ++k2) {
        const int rb = wc * 64 + n * 16 + l15;
        bfr[n][k2] =
            *(const short8*)&Bc[rb * 64 + (((l4 + k2 * 4) ^ (rb & 7)) << 3)];
      }
#pragma unroll
    for (int i = 0; i < 8; ++i) {
      short8 af[2];
#pragma unroll
      for (int k2 = 0; k2 < 2; ++k2) {
        const int ra = wr * 128 + i * 16 + l15;
        af[k2] =
            *(const short8*)&Ac[ra * 64 + (((l4 + k2 * 4) ^ (ra & 7)) << 3)];
      }
#pragma unroll
      for (int n = 0; n < 4; ++n)
#pragma unroll
        for (int k2 = 0; k2 < 2; ++k2)
          acc[i][n] = __builtin_amdgcn_mfma_f32_16x16x32_bf16(
              af[k2], bfr[n][k2], acc[i][n], 0, 0, 0);
    }
  };

  auto epilogue = [&](int col0) {
    /* step A: wave-local per-row max over this wave's 64 cols */
#pragma unroll
    for (int i = 0; i < 8; ++i)
#pragma unroll
      for (int r = 0; r < 4; ++r) {
        float v = fmaxf(fmaxf(acc[i][0][r], acc[i][1][r]),
                        fmaxf(acc[i][2][r], acc[i][3][r]));
#pragma unroll
        for (int off = 1; off < 16; off <<= 1)
          v = fmaxf(v, __shfl_xor(v, off, 64));
        if (l15 == 0) redm[wr * 128 + i * 16 + l4 * 4 + r][wc] = v;
      }
    __syncthreads();
    /* step B: cross-wave max + threshold + collect (reads old runm) */
#pragma unroll
    for (int i = 0; i < 8; ++i)
#pragma unroll
      for (int r = 0; r < 4; ++r) {
        const int rowt = wr * 128 + i * 16 + l4 * 4 + r;
        const float4 m4 = *(const float4*)redm[rowt];
        const float nm =
            fmaxf(runm[rowt], fmaxf(fmaxf(m4.x, m4.y), fmaxf(m4.z, m4.w)));
        const float th = nm - TAU;
        const int rowg = row0 + rowt;
#pragma unroll
        for (int n = 0; n < 4; ++n) {
          if (acc[i][n][r] >= th) {
            const int slot = atomicAdd(&counts[rowg], 1);
            if (slot < MAXC)
              cands[rowg * MAXC + slot] = col0 + wc * 64 + n * 16 + l15;
          }
        }
#pragma unroll
        for (int n = 0; n < 4; ++n) acc[i][n][r] = 0.f;
      }
    __syncthreads();
    /* step C: designated lanes update running max */
    if (wc == 0 && l15 == 0) {
#pragma unroll
      for (int i = 0; i < 8; ++i)
#pragma unroll
        for (int r = 0; r < 4; ++r) {
          const int rowt = wr * 128 + i * 16 + l4 * 4 + r;
          const float4 m4 = *(const float4*)redm[rowt];
          runm[rowt] =
              fmaxf(runm[rowt], fmaxf(fmaxf(m4.x, m4.y), fmaxf(m4.z, m4.w)));
        }
    }
  };

  /* prologue: K-tile 0 into As0/Bs0 */
  stage(As0, Bs0, 0);

  for (int gk = 0; gk < NGK; gk += 2) {
    /* publish even tile; immediately issue odd tile's stage */
    asm volatile("s_waitcnt vmcnt(0)" ::: "memory");
    __builtin_amdgcn_s_barrier();
    stage(As1, Bs1, gk + 1);
    compute(As0, Bs0);

    /* publish odd tile; immediately issue next even tile's stage */
    asm volatile("s_waitcnt vmcnt(0)" ::: "memory");
    __builtin_amdgcn_s_barrier();
    stage(As0, Bs0, gk + 2);
    compute(As1, Bs1);

    /* col-tile boundary: (gk+1)&7 == 7  <=>  gk&7 == 6 */
    if ((gk & 7) == 6) epilogue(seg0 + (gk >> 3) * BNG);
  }
}

// ---------------------------------------------------------------------------
// fp32-EMULATED rescore (unchanged).
// ---------------------------------------------------------------------------
__global__ __launch_bounds__(256) void k_rescore(
    const float* __restrict__ z, const float* __restrict__ normz,
    const float* __restrict__ cnf, const int* __restrict__ counts,
    const int* __restrict__ cands, int* __restrict__ bestk) {
  __shared__ float zn[4][DIM];
  const int wv = threadIdx.x >> 6;
  const int lane = threadIdx.x & 63;
  const int row = blockIdx.x * 4 + wv;
  const float n = normz[row];
  const float* zr = z + (size_t)row * DIM;
#pragma unroll
  for (int j = 0; j < 8; ++j) {
    const int d = lane * 8 + j;
    zn[wv][d] = __fdiv_rn(zr[d], n);
  }
  __syncthreads();
  const int cnt = counts[row];
  const bool fullscan = (cnt <= 0) || (cnt > MAXC);
  ull best = 0ull;
  if (!fullscan) {
    const int idx = (lane < cnt) ? lane : (cnt - 1);
    const int k = cands[row * MAXC + idx] & (KCODES - 1);
    const float* cr = cnf + (size_t)k * DIM;
    float a1 = 0.f, a2 = 0.f;
    for (int d = 0; d < CHAINSPLIT; d += 4) {
      const float4 c = *(const float4*)(cr + d);
      a1 = fmaf(zn[wv][d], c.x, a1);
      a1 = fmaf(zn[wv][d + 1], c.y, a1);
      a1 = fmaf(zn[wv][d + 2], c.z, a1);
      a1 = fmaf(zn[wv][d + 3], c.w, a1);
    }
    for (int d = CHAINSPLIT; d < DIM; d += 4) {
      const float4 c = *(const float4*)(cr + d);
      a2 = fmaf(zn[wv][d], c.x, a2);
      a2 = fmaf(zn[wv][d + 1], c.y, a2);
      a2 = fmaf(zn[wv][d + 2], c.z, a2);
      a2 = fmaf(zn[wv][d + 3], c.w, a2);
    }
    const float s = __fadd_rn(a1, a2);
    if (lane < cnt) best = ((ull)fkey(s) << 32) | (ull)(8191 - k);
  } else {
    for (int base = 0; base < KCODES; base += 64) {
      const int k = base + lane;
      const float* cr = cnf + (size_t)k * DIM;
      float a1 = 0.f, a2 = 0.f;
      for (int d = 0; d < CHAINSPLIT; d += 4) {
        const float4 c = *(const float4*)(cr + d);
        a1 = fmaf(zn[wv][d], c.x, a1);
        a1 = fmaf(zn[wv][d + 1], c.y, a1);
        a1 = fmaf(zn[wv][d + 2], c.z, a1);
        a1 = fmaf(zn[wv][d + 3], c.w, a1);
      }
      for (int d = CHAINSPLIT; d < DIM; d += 4) {
        const float4 c = *(const float4*)(cr + d);
        a2 = fmaf(zn[wv][d], c.x, a2);
        a2 = fmaf(zn[wv][d + 1], c.y, a2);
        a2 = fmaf(zn[wv][d + 2], c.z, a2);
        a2 = fmaf(zn[wv][d + 3], c.w, a2);
      }
      const float s = __fadd_rn(a1, a2);
      const ull q = ((ull)fkey(s) << 32) | (ull)(8191 - k);
      best = (q > best) ? q : best;
    }
  }
#pragma unroll
  for (int off = 1; off < 64; off <<= 1) {
    const ull o = __shfl_xor(best, off, 64);
    best = (o > best) ? o : best;
  }
  if (lane == 0) bestk[row] = 8191 - (int)(best & 0xFFFFFFFFull);
}

// ---------------------------------------------------------------------------
// Output (unchanged).
// ---------------------------------------------------------------------------
__global__ __launch_bounds__(256) void k_output(
    const float* __restrict__ z, const float* __restrict__ normz,
    const float* __restrict__ cnf, const int* __restrict__ bestk,
    float* __restrict__ out, float* __restrict__ lossacc) {
  const int wv = threadIdx.x >> 6;
  const int lane = threadIdx.x & 63;
  const int row = blockIdx.x * 4 + wv;
  const int k = bestk[row];
  const float n = normz[row];
  const float4* cr = (const float4*)(cnf + (size_t)k * DIM);
  const float4* zr = (const float4*)(z + (size_t)row * DIM);
  float ss = 0.0f;
  float4* orow = (float4*)(out + (size_t)row * DIM);
#pragma unroll
  for (int h = 0; h < 2; ++h) {
    const float4 q = cr[lane + 64 * h];
    const float4 zv = zr[lane + 64 * h];
    orow[lane + 64 * h] = q;
    const float d0 = q.x - __fdiv_rn(zv.x, n);
    const float d1 = q.y - __fdiv_rn(zv.y, n);
    const float d2 = q.z - __fdiv_rn(zv.z, n);
    const float d3 = q.w - __fdiv_rn(zv.w, n);
    ss += d0 * d0 + d1 * d1 + d2 * d2 + d3 * d3;
  }
#pragma unroll
  for (int off = 1; off < 64; off <<= 1) ss += __shfl_xor(ss, off, 64);
  if (lane == 0) {
    atomicAdd(lossacc, ss);
    out[(size_t)NROWS * DIM + row] = (float)k;
  }
}

__global__ void k_loss_final(const float* __restrict__ lossacc,
                             float* __restrict__ out) {
  if (threadIdx.x == 0 && blockIdx.x == 0)
    out[(size_t)NROWS * DIM + NROWS] =
        1.5f * (*lossacc) / (float)((size_t)NROWS * DIM);
}

// ---------------------------------------------------------------------------
extern "C" void kernel_launch(void* const* d_in, const int* in_sizes, int n_in,
                              void* d_out, int out_size, void* d_ws, size_t ws_size,
                              hipStream_t stream) {
  const float* z = (const float*)d_in[0];
  const float* cb = (const float*)d_in[1];
  char* ws = (char*)d_ws;
  // workspace layout, ~64.5 MB total
  float* normz = (float*)(ws);                             // 131072
  float* normc = (float*)(ws + 131072);                    // 32768
  int* counts = (int*)(ws + 163840);                       // 131072
  int* bestk = (int*)(ws + 294912);                        // 131072
  float* lossacc = (float*)(ws + 425984);                  // 4 (padded)
  int* cands = (int*)(ws + 458752);                        // 8388608
  unsigned short* znb = (unsigned short*)(ws + 8847360);   // 33554432
  unsigned short* cnb = (unsigned short*)(ws + 42401792);  // 8388608
  float* cnf = (float*)(ws + 50790400);                    // 16777216
  float* out = (float*)d_out;

  k_rownorm2<<<dim3(NROWS / 32 + KCODES / 32), dim3(256), 0, stream>>>(
      z, cb, normz, normc, counts, lossacc);
  k_normstore2<<<dim3(NROWS / 4 + KCODES / 4), dim3(256), 0, stream>>>(
      z, cb, normz, normc, znb, cnb, cnf);
  k_gemm_collect<<<dim3(NROWS / BMG, KSPLIT), dim3(512), 0, stream>>>(znb, cnb,
                                                                      counts, cands);
  k_rescore<<<dim3(NROWS / 4), dim3(256), 0, stream>>>(z, normz, cnf, counts,
                                                       cands, bestk);
  k_output<<<dim3(NROWS / 4), dim3(256), 0, stream>>>(z, normz, cnf, bestk, out,
                                                      lossacc);
  k_loss_final<<<dim3(1), dim3(64), 0, stream>>>(lossacc, out);
}

// Round 4
// 1183.899 us; speedup vs baseline: 1.0346x; 1.0202x over previous
//
#include <hip/hip_runtime.h>
#include <stdint.h>
#include <stddef.h>

#define NROWS 32768
#define KCODES 8192
#define DIM 512

/* ---- filter GEMM: 256^2 tile, 16 waves, counted-vmcnt double buffer ---- */
#define BMG 256
#define BNG 256
#define BKG 64
#define KSPLIT 2
#define SEGC (KCODES / KSPLIT)          /* 4096 */
#define NGK ((SEGC / BNG) * (DIM / BKG)) /* 128 K-tiles per block */
#define TAU 1.5e-3f
#define MAXC 64
#define CHAINSPLIT 384 /* OpenBLAS sgemm kc */

typedef __attribute__((ext_vector_type(8))) short short8;
typedef __attribute__((ext_vector_type(4))) float floatx4;
typedef unsigned long long ull;

static __device__ __forceinline__ unsigned short f2bf(float f) {
  unsigned u = __float_as_uint(f);
  unsigned r = (u + 0x7FFFu + ((u >> 16) & 1u)) >> 16;
  return (unsigned short)r;
}
// monotone float->uint key (order-preserving for finite floats)
static __device__ __forceinline__ unsigned fkey(float s) {
  unsigned b = __float_as_uint(s);
  return b ^ (((int)b < 0) ? 0xFFFFFFFFu : 0x80000000u);
}
static __device__ __forceinline__ float fkey_inv(unsigned u) {
  return __uint_as_float((u & 0x80000000u) ? (u ^ 0x80000000u) : ~u);
}

#define GLDS16(g, l)                                                        \
  __builtin_amdgcn_global_load_lds(                                         \
      (const __attribute__((address_space(1))) unsigned int*)(g),           \
      (__attribute__((address_space(3))) unsigned int*)(l), 16, 0, 0)

// ---------------------------------------------------------------------------
// numpy-exact row norm, z and codebook fused into one dispatch.
// Also zero-inits counts, gmax (global running-max keys) and lossacc.
// ---------------------------------------------------------------------------
__global__ __launch_bounds__(256) void k_rownorm2(
    const float* __restrict__ z, const float* __restrict__ cb,
    float* __restrict__ normz, float* __restrict__ normc,
    int* __restrict__ counts, unsigned* __restrict__ gmax,
    float* __restrict__ lossacc) {
  const int tid = threadIdx.x;
  const int j = tid & 7;
  const int b = blockIdx.x;
  const bool isz = (b < NROWS / 32);
  const float* x = isz ? z : cb;
  float* nout = isz ? normz : normc;
  const int row = (isz ? b : (b - NROWS / 32)) * 32 + (tid >> 3);
  if (isz && j == 0) {
    counts[row] = 0;
    gmax[row] = 0u; /* decodes below any fkey(score) */
  }
  if (b == 0 && tid == 0) *lossacc = 0.0f;
  const float* xr = x + (size_t)row * DIM;
  float blk[4];
#pragma unroll
  for (int bb = 0; bb < 4; ++bb) {
    const float* p = xr + bb * 128;
    float r = __fmul_rn(p[j], p[j]);
    for (int i = 8; i < 128; i += 8) {
      const float t = p[i + j];
      r = __fadd_rn(r, __fmul_rn(t, t));
    }
    r = __fadd_rn(r, __shfl_xor(r, 1, 64));
    r = __fadd_rn(r, __shfl_xor(r, 2, 64));
    r = __fadd_rn(r, __shfl_xor(r, 4, 64));
    blk[bb] = r;
  }
  const float tot =
      __fadd_rn(__fadd_rn(blk[0], blk[1]), __fadd_rn(blk[2], blk[3]));
  if (j == 0) nout[row] = fmaxf(__fsqrt_rn(tot), 1e-12f);
}

// ---------------------------------------------------------------------------
// Normalized rows, z and codebook fused. Bit-identical math.
// ---------------------------------------------------------------------------
__global__ __launch_bounds__(256) void k_normstore2(
    const float* __restrict__ z, const float* __restrict__ cb,
    const float* __restrict__ normz, const float* __restrict__ normc,
    unsigned short* __restrict__ znb, unsigned short* __restrict__ cnb,
    float* __restrict__ cnf) {
  const int wv = threadIdx.x >> 6;
  const int lane = threadIdx.x & 63;
  const int b = blockIdx.x;
  const bool isz = (b < NROWS / 4);
  const int row = (isz ? b : (b - NROWS / 4)) * 4 + wv;
  const float* x = isz ? z : cb;
  const float n = (isz ? normz : normc)[row];
  unsigned short* xb = isz ? znb : cnb;
  float* xf = isz ? (float*)nullptr : cnf;
  const float4* xr = (const float4*)(x + (size_t)row * DIM);
#pragma unroll
  for (int h = 0; h < 2; ++h) {
    const float4 v = xr[lane + 64 * h];
    const float q0 = __fdiv_rn(v.x, n);
    const float q1 = __fdiv_rn(v.y, n);
    const float q2 = __fdiv_rn(v.z, n);
    const float q3 = __fdiv_rn(v.w, n);
    if (xf != nullptr)
      ((float4*)(xf + (size_t)row * DIM))[lane + 64 * h] =
          make_float4(q0, q1, q2, q3);
    *(ushort4*)(xb + (size_t)row * DIM + 256 * h + 4 * lane) =
        make_ushort4(f2bf(q0), f2bf(q1), f2bf(q2), f2bf(q3));
  }
}

// ---------------------------------------------------------------------------
// bf16 MFMA filter GEMM: 256x256 tile, 16 waves (4M x 4N, wave tile 64x64,
// acc=64 regs -> 4 waves/SIMD = 16 waves/CU, 2x the VMEM queue depth of the
// 8-wave variant -- targets the latency x MLP staging floor). Double-buffered
// LDS (128KB) with COUNTED vmcnt(4): each K-tile's 4 loads/thread stay in
// flight across a full compute phase; the counter never drains to 0 in the
// main loop. Collect threshold uses a global cross-segment running max
// (atomicMax in monotone-key space, device-scope) -> tighter bands, cnt==1
// for most rows. Granule-XOR LDS swizzle via pre-swizzled global source.
// Grid: (128, KSPLIT=2) = 256 blocks; bijective XCD swizzle gives each XCD
// one 4MB cnb segment slice.
// ---------------------------------------------------------------------------
__global__ __launch_bounds__(1024, 4) void k_gemm_collect(
    const unsigned short* __restrict__ znb, const unsigned short* __restrict__ cnb,
    int* __restrict__ counts, int* __restrict__ cands,
    unsigned* __restrict__ gmax) {
  __shared__ __align__(16) short As0[BMG * BKG]; /* 32KB */
  __shared__ __align__(16) short Bs0[BNG * BKG]; /* 32KB */
  __shared__ __align__(16) short As1[BMG * BKG]; /* 32KB */
  __shared__ __align__(16) short Bs1[BNG * BKG]; /* 32KB */
  __shared__ __align__(16) float redm[256][4];

  const int tid = threadIdx.x;
  const int lane = tid & 63;
  const int w = tid >> 6; /* wave 0..15 */
  const int wm = w >> 2;  /* M quarter: rows wm*64.. */
  const int wn = w & 3;   /* N quarter: cols wn*64.. */
  const int l15 = lane & 15;
  const int l4 = lane >> 4;

  /* XCD-aware bijective swizzle: 256 blocks -> 32 contiguous per XCD */
  const int bid = blockIdx.y * (NROWS / BMG) + blockIdx.x;
  const int logical = (bid & 7) * 32 + (bid >> 3);
  const int row0 = (logical & (NROWS / BMG - 1)) * BMG;
  const int seg0 = (logical >> 7) * SEGC;

  /* per-lane loop-invariant staging geometry (shorts) */
  int aoff[2], boff[2], loff[2];
#pragma unroll
  for (int l = 0; l < 2; ++l) {
    const int g = (l * 16 + w) * 64 + lane; /* granule id 0..2047 */
    const int r = g >> 3;                   /* tile row 0..255 */
    const int cg = (g & 7) ^ (r & 7);       /* pre-swizzled source granule */
    aoff[l] = (row0 + r) * DIM + cg * 8;
    boff[l] = r * DIM + cg * 8;
    loff[l] = (l * 16 + w) * 512;
  }

  auto stage = [&](short* Ad, short* Bd, int gk) {
    if (gk >= NGK) gk = NGK - 2; /* tail: idempotent re-stage of dead buffer */
    const int d0 = (gk & 7) * BKG;
    const size_t cb0 = (size_t)(seg0 + (gk >> 3) * BNG) * DIM;
#pragma unroll
    for (int l = 0; l < 2; ++l) {
      GLDS16(znb + (size_t)aoff[l] + d0, Ad + loff[l]);
      GLDS16(cnb + cb0 + boff[l] + d0, Bd + loff[l]);
    }
  };

  floatx4 acc[4][4];
#pragma unroll
  for (int i = 0; i < 4; ++i)
#pragma unroll
    for (int n = 0; n < 4; ++n) {
      floatx4 zz = {0.f, 0.f, 0.f, 0.f};
      acc[i][n] = zz;
    }

  /* full K-tile compute for wave tile 64x64: 16 ds_read_b128 + 32 MFMA */
  auto compute = [&](const short* Ac, const short* Bc) {
    short8 bfr[4][2];
#pragma unroll
    for (int n = 0; n < 4; ++n)
#pragma unroll
      for (int k2 = 0; k2 < 2; ++k2) {
        const int rb = wn * 64 + n * 16 + l15;
        bfr[n][k2] =
            *(const short8*)&Bc[rb * 64 + (((l4 + k2 * 4) ^ (rb & 7)) << 3)];
      }
#pragma unroll
    for (int i = 0; i < 4; ++i) {
      short8 af[2];
#pragma unroll
      for (int k2 = 0; k2 < 2; ++k2) {
        const int ra = wm * 64 + i * 16 + l15;
        af[k2] =
            *(const short8*)&Ac[ra * 64 + (((l4 + k2 * 4) ^ (ra & 7)) << 3)];
      }
#pragma unroll
      for (int n = 0; n < 4; ++n)
#pragma unroll
        for (int k2 = 0; k2 < 2; ++k2)
          acc[i][n] = __builtin_amdgcn_mfma_f32_16x16x32_bf16(
              af[k2], bfr[n][k2], acc[i][n], 0, 0, 0);
    }
  };

  auto epilogue = [&](int col0) {
    /* step A: wave-local per-row max over this wave's 64 cols */
#pragma unroll
    for (int i = 0; i < 4; ++i)
#pragma unroll
      for (int r = 0; r < 4; ++r) {
        float v = fmaxf(fmaxf(acc[i][0][r], acc[i][1][r]),
                        fmaxf(acc[i][2][r], acc[i][3][r]));
#pragma unroll
        for (int off = 1; off < 16; off <<= 1)
          v = fmaxf(v, __shfl_xor(v, off, 64));
        if (l15 == 0) redm[wm * 64 + i * 16 + l4 * 4 + r][wn] = v;
      }
    __syncthreads();
    /* step B: cross-wave max -> global atomicMax threshold -> collect */
#pragma unroll
    for (int i = 0; i < 4; ++i)
#pragma unroll
      for (int r = 0; r < 4; ++r) {
        const int rowt = wm * 64 + i * 16 + l4 * 4 + r;
        const float4 m4 = *(const float4*)redm[rowt];
        const float nm = fmaxf(fmaxf(m4.x, m4.y), fmaxf(m4.z, m4.w));
        const int rowg = row0 + rowt;
        const unsigned key = fkey(nm);
        unsigned thk = 0u;
        if (l15 == 0) {
          const unsigned old = atomicMax(&gmax[rowg], key);
          thk = old > key ? old : key;
        }
        thk = __shfl(thk, lane & 48, 64); /* broadcast from l15==0 of group */
        const float th = fkey_inv(thk) - TAU;
#pragma unroll
        for (int n = 0; n < 4; ++n) {
          if (acc[i][n][r] >= th) {
            const int slot = atomicAdd(&counts[rowg], 1);
            if (slot < MAXC)
              cands[rowg * MAXC + slot] = col0 + wn * 64 + n * 16 + l15;
          }
        }
#pragma unroll
        for (int n = 0; n < 4; ++n) acc[i][n][r] = 0.f;
      }
    __syncthreads();
  };

  /* prologue: K-tile 0 into As0/Bs0 (4 loads in flight) */
  stage(As0, Bs0, 0);

  for (int gk = 0; gk < NGK; gk += 2) {
    /* even tile: issue odd tile's stage, counted-wait on even tile's loads */
    stage(As1, Bs1, gk + 1);
    asm volatile("s_waitcnt vmcnt(4)" ::: "memory");
    __builtin_amdgcn_s_barrier();
    compute(As0, Bs0);
    __builtin_amdgcn_s_barrier();

    /* odd tile: issue next even tile's stage, counted-wait on odd's loads */
    stage(As0, Bs0, gk + 2);
    asm volatile("s_waitcnt vmcnt(4)" ::: "memory");
    __builtin_amdgcn_s_barrier();
    compute(As1, Bs1);
    __builtin_amdgcn_s_barrier();

    /* col-tile boundary: (gk+1)&7 == 7  <=>  gk&7 == 6 */
    if ((gk & 7) == 6) epilogue(seg0 + (gk >> 3) * BNG);
  }
}

// ---------------------------------------------------------------------------
// fp32-EMULATED rescore + fused output. cnt==1 -> the single candidate IS the
// bf16 argmax with no rival in the TAU band -> exact argmax by the same
// premise the filter already relies on; skip the dot entirely. Output phase
// reads zn from LDS (bits == __fdiv_rn(z,n), identical to old k_output).
// ---------------------------------------------------------------------------
__global__ __launch_bounds__(256) void k_rescore_out(
    const float* __restrict__ z, const float* __restrict__ normz,
    const float* __restrict__ cnf, const int* __restrict__ counts,
    const int* __restrict__ cands, float* __restrict__ out,
    float* __restrict__ lossacc) {
  __shared__ __align__(16) float zn[4][DIM];
  const int wv = threadIdx.x >> 6;
  const int lane = threadIdx.x & 63;
  const int row = blockIdx.x * 4 + wv;
  const float n = normz[row];
  const float* zr = z + (size_t)row * DIM;
#pragma unroll
  for (int j = 0; j < 8; ++j) {
    const int d = lane * 8 + j;
    zn[wv][d] = __fdiv_rn(zr[d], n);
  }
  __syncthreads();
  const int cnt = counts[row];
  int bk;
  if (cnt == 1) {
    bk = cands[row * MAXC] & (KCODES - 1);
  } else {
    const bool fullscan = (cnt <= 0) || (cnt > MAXC);
    ull best = 0ull;
    if (!fullscan) {
      const int idx = (lane < cnt) ? lane : (cnt - 1);
      const int k = cands[row * MAXC + idx] & (KCODES - 1);
      const float* cr = cnf + (size_t)k * DIM;
      float a1 = 0.f, a2 = 0.f;
      for (int d = 0; d < CHAINSPLIT; d += 4) {
        const float4 c = *(const float4*)(cr + d);
        a1 = fmaf(zn[wv][d], c.x, a1);
        a1 = fmaf(zn[wv][d + 1], c.y, a1);
        a1 = fmaf(zn[wv][d + 2], c.z, a1);
        a1 = fmaf(zn[wv][d + 3], c.w, a1);
      }
      for (int d = CHAINSPLIT; d < DIM; d += 4) {
        const float4 c = *(const float4*)(cr + d);
        a2 = fmaf(zn[wv][d], c.x, a2);
        a2 = fmaf(zn[wv][d + 1], c.y, a2);
        a2 = fmaf(zn[wv][d + 2], c.z, a2);
        a2 = fmaf(zn[wv][d + 3], c.w, a2);
      }
      const float s = __fadd_rn(a1, a2);
      if (lane < cnt) best = ((ull)fkey(s) << 32) | (ull)(8191 - k);
    } else {
      for (int base = 0; base < KCODES; base += 64) {
        const int k = base + lane;
        const float* cr = cnf + (size_t)k * DIM;
        float a1 = 0.f, a2 = 0.f;
        for (int d = 0; d < CHAINSPLIT; d += 4) {
          const float4 c = *(const float4*)(cr + d);
          a1 = fmaf(zn[wv][d], c.x, a1);
          a1 = fmaf(zn[wv][d + 1], c.y, a1);
          a1 = fmaf(zn[wv][d + 2], c.z, a1);
          a1 = fmaf(zn[wv][d + 3], c.w, a1);
        }
        for (int d = CHAINSPLIT; d < DIM; d += 4) {
          const float4 c = *(const float4*)(cr + d);
          a2 = fmaf(zn[wv][d], c.x, a2);
          a2 = fmaf(zn[wv][d + 1], c.y, a2);
          a2 = fmaf(zn[wv][d + 2], c.z, a2);
          a2 = fmaf(zn[wv][d + 3], c.w, a2);
        }
        const float s = __fadd_rn(a1, a2);
        const ull q = ((ull)fkey(s) << 32) | (ull)(8191 - k);
        best = (q > best) ? q : best;
      }
    }
#pragma unroll
    for (int off = 1; off < 64; off <<= 1) {
      const ull o = __shfl_xor(best, off, 64);
      best = (o > best) ? o : best;
    }
    bk = 8191 - (int)(best & 0xFFFFFFFFull);
  }

  /* ---- fused output: zq rows, index, loss (bit-identical to k_output) */
  const float4* cr4 = (const float4*)(cnf + (size_t)bk * DIM);
  const float4* znr = (const float4*)zn[wv];
  float ss = 0.0f;
  float4* orow = (float4*)(out + (size_t)row * DIM);
#pragma unroll
  for (int h = 0; h < 2; ++h) {
    const float4 q = cr4[lane + 64 * h];
    const float4 zv = znr[lane + 64 * h];
    orow[lane + 64 * h] = q;
    const float d0 = q.x - zv.x;
    const float d1 = q.y - zv.y;
    const float d2 = q.z - zv.z;
    const float d3 = q.w - zv.w;
    ss += d0 * d0 + d1 * d1 + d2 * d2 + d3 * d3;
  }
#pragma unroll
  for (int off = 1; off < 64; off <<= 1) ss += __shfl_xor(ss, off, 64);
  if (lane == 0) {
    atomicAdd(lossacc, ss);
    out[(size_t)NROWS * DIM + row] = (float)bk;
  }
}

__global__ void k_loss_final(const float* __restrict__ lossacc,
                             float* __restrict__ out) {
  if (threadIdx.x == 0 && blockIdx.x == 0)
    out[(size_t)NROWS * DIM + NROWS] =
        1.5f * (*lossacc) / (float)((size_t)NROWS * DIM);
}

// ---------------------------------------------------------------------------
extern "C" void kernel_launch(void* const* d_in, const int* in_sizes, int n_in,
                              void* d_out, int out_size, void* d_ws, size_t ws_size,
                              hipStream_t stream) {
  const float* z = (const float*)d_in[0];
  const float* cb = (const float*)d_in[1];
  char* ws = (char*)d_ws;
  // workspace layout (~67.6 MB total, unchanged footprint)
  float* normz = (float*)(ws);                             // 131072
  float* normc = (float*)(ws + 131072);                    // 32768
  int* counts = (int*)(ws + 163840);                       // 131072
  unsigned* gmax = (unsigned*)(ws + 294912);               // 131072 (ex-bestk)
  float* lossacc = (float*)(ws + 425984);                  // 4 (padded)
  int* cands = (int*)(ws + 458752);                        // 8388608
  unsigned short* znb = (unsigned short*)(ws + 8847360);   // 33554432
  unsigned short* cnb = (unsigned short*)(ws + 42401792);  // 8388608
  float* cnf = (float*)(ws + 50790400);                    // 16777216
  float* out = (float*)d_out;

  k_rownorm2<<<dim3(NROWS / 32 + KCODES / 32), dim3(256), 0, stream>>>(
      z, cb, normz, normc, counts, gmax, lossacc);
  k_normstore2<<<dim3(NROWS / 4 + KCODES / 4), dim3(256), 0, stream>>>(
      z, cb, normz, normc, znb, cnb, cnf);
  k_gemm_collect<<<dim3(NROWS / BMG, KSPLIT), dim3(1024), 0, stream>>>(
      znb, cnb, counts, cands, gmax);
  k_rescore_out<<<dim3(NROWS / 4), dim3(256), 0, stream>>>(
      z, normz, cnf, counts, cands, out, lossacc);
  k_loss_final<<<dim3(1), dim3(64), 0, stream>>>(lossacc, out);
}

// Round 5
// 1001.508 us; speedup vs baseline: 1.2230x; 1.1821x over previous
//
#include <hip/hip_runtime.h>
#include <stdint.h>
#include <stddef.h>

#define NROWS 32768
#define KCODES 8192
#define DIM 512

/* ---- filter GEMM: R3 core (8 waves, 256^2 tile, 1 drain per K-tile) ---- */
#define BMG 256
#define BNG 256
#define BKG 64
#define KSPLIT 2
#define SEGC (KCODES / KSPLIT)          /* 4096 */
#define NGK ((SEGC / BNG) * (DIM / BKG)) /* 128 K-tiles per block */
#define TAU 1.5e-3f
#define MAXC 64
#define CHAINSPLIT 384 /* OpenBLAS sgemm kc */

typedef __attribute__((ext_vector_type(8))) short short8;
typedef __attribute__((ext_vector_type(4))) float floatx4;
typedef unsigned long long ull;

static __device__ __forceinline__ unsigned short f2bf(float f) {
  unsigned u = __float_as_uint(f);
  unsigned r = (u + 0x7FFFu + ((u >> 16) & 1u)) >> 16;
  return (unsigned short)r;
}
// monotone float->uint key (order-preserving for finite floats)
static __device__ __forceinline__ unsigned fkey(float s) {
  unsigned b = __float_as_uint(s);
  return b ^ (((int)b < 0) ? 0xFFFFFFFFu : 0x80000000u);
}
static __device__ __forceinline__ float fkey_inv(unsigned u) {
  return __uint_as_float((u & 0x80000000u) ? (u ^ 0x80000000u) : ~u);
}

#define GLDS16(g, l)                                                        \
  __builtin_amdgcn_global_load_lds(                                         \
      (const __attribute__((address_space(1))) unsigned int*)(g),           \
      (__attribute__((address_space(3))) unsigned int*)(l), 16, 0, 0)

// ---------------------------------------------------------------------------
// numpy-exact row norm, z and codebook fused into one dispatch.
// Also zero-inits counts, gmax (global running-max keys) and lossacc.
// ---------------------------------------------------------------------------
__global__ __launch_bounds__(256) void k_rownorm2(
    const float* __restrict__ z, const float* __restrict__ cb,
    float* __restrict__ normz, float* __restrict__ normc,
    int* __restrict__ counts, unsigned* __restrict__ gmax,
    float* __restrict__ lossacc) {
  const int tid = threadIdx.x;
  const int j = tid & 7;
  const int b = blockIdx.x;
  const bool isz = (b < NROWS / 32);
  const float* x = isz ? z : cb;
  float* nout = isz ? normz : normc;
  const int row = (isz ? b : (b - NROWS / 32)) * 32 + (tid >> 3);
  if (isz && j == 0) {
    counts[row] = 0;
    gmax[row] = 0u; /* decodes below any fkey(score) */
  }
  if (b == 0 && tid == 0) *lossacc = 0.0f;
  const float* xr = x + (size_t)row * DIM;
  float blk[4];
#pragma unroll
  for (int bb = 0; bb < 4; ++bb) {
    const float* p = xr + bb * 128;
    float r = __fmul_rn(p[j], p[j]);
    for (int i = 8; i < 128; i += 8) {
      const float t = p[i + j];
      r = __fadd_rn(r, __fmul_rn(t, t));
    }
    r = __fadd_rn(r, __shfl_xor(r, 1, 64));
    r = __fadd_rn(r, __shfl_xor(r, 2, 64));
    r = __fadd_rn(r, __shfl_xor(r, 4, 64));
    blk[bb] = r;
  }
  const float tot =
      __fadd_rn(__fadd_rn(blk[0], blk[1]), __fadd_rn(blk[2], blk[3]));
  if (j == 0) nout[row] = fmaxf(__fsqrt_rn(tot), 1e-12f);
}

// ---------------------------------------------------------------------------
// Normalized rows, z and codebook fused. Bit-identical math.
// ---------------------------------------------------------------------------
__global__ __launch_bounds__(256) void k_normstore2(
    const float* __restrict__ z, const float* __restrict__ cb,
    const float* __restrict__ normz, const float* __restrict__ normc,
    unsigned short* __restrict__ znb, unsigned short* __restrict__ cnb,
    float* __restrict__ cnf) {
  const int wv = threadIdx.x >> 6;
  const int lane = threadIdx.x & 63;
  const int b = blockIdx.x;
  const bool isz = (b < NROWS / 4);
  const int row = (isz ? b : (b - NROWS / 4)) * 4 + wv;
  const float* x = isz ? z : cb;
  const float n = (isz ? normz : normc)[row];
  unsigned short* xb = isz ? znb : cnb;
  float* xf = isz ? (float*)nullptr : cnf;
  const float4* xr = (const float4*)(x + (size_t)row * DIM);
#pragma unroll
  for (int h = 0; h < 2; ++h) {
    const float4 v = xr[lane + 64 * h];
    const float q0 = __fdiv_rn(v.x, n);
    const float q1 = __fdiv_rn(v.y, n);
    const float q2 = __fdiv_rn(v.z, n);
    const float q3 = __fdiv_rn(v.w, n);
    if (xf != nullptr)
      ((float4*)(xf + (size_t)row * DIM))[lane + 64 * h] =
          make_float4(q0, q1, q2, q3);
    *(ushort4*)(xb + (size_t)row * DIM + 256 * h + 4 * lane) =
        make_ushort4(f2bf(q0), f2bf(q1), f2bf(q2), f2bf(q3));
  }
}

// ---------------------------------------------------------------------------
// bf16 MFMA filter GEMM: EXACT R3 core (measured 490us): 8 waves (2M x 4N,
// wave tile 128x64), 256x256 tile, double-buffered LDS, one vmcnt(0) drain +
// barrier per BK=64 K-tile, stage of tile t+1 issued right after the barrier
// publishing tile t. Only the collect epilogue changed vs R3: the block-local
// running max is replaced by a global cross-segment atomicMax (gmax, monotone
// key space). Flat step: 8 waves x 32 rows, one lane per row, one atomicMax
// per row per col-tile; thresholds published to thbuf (LDS) and read by the
// collect loop. Tightened thresholds -> cnt==1 for most rows -> rescore
// becomes an index copy. Collection stays conservative: th <= final_max-TAU
// at all times, so every code within TAU of the final bf16 max is collected.
// ---------------------------------------------------------------------------
__global__ __launch_bounds__(512, 2) void k_gemm_collect(
    const unsigned short* __restrict__ znb, const unsigned short* __restrict__ cnb,
    int* __restrict__ counts, int* __restrict__ cands,
    unsigned* __restrict__ gmax) {
  __shared__ __align__(16) short As0[BMG * BKG]; /* 32KB */
  __shared__ __align__(16) short Bs0[BNG * BKG]; /* 32KB */
  __shared__ __align__(16) short As1[BMG * BKG]; /* 32KB */
  __shared__ __align__(16) short Bs1[BNG * BKG]; /* 32KB */
  __shared__ __align__(16) float redm[256][4];
  __shared__ float thbuf[256];

  const int tid = threadIdx.x;
  const int lane = tid & 63;
  const int w = tid >> 6; /* wave 0..7 */
  const int wr = w >> 2;  /* M half: rows wr*128.. */
  const int wc = w & 3;   /* N quarter: cols wc*64.. */
  const int l15 = lane & 15;
  const int l4 = lane >> 4;

  /* XCD-aware bijective swizzle: 256 blocks -> 32 contiguous per XCD */
  const int bid = blockIdx.y * (NROWS / BMG) + blockIdx.x;
  const int logical = (bid & 7) * 32 + (bid >> 3);
  const int row0 = (logical & (NROWS / BMG - 1)) * BMG;
  const int seg0 = (logical >> 7) * SEGC;

  /* per-lane loop-invariant staging geometry (shorts) */
  int aoff[4], boff[4], loff[4];
#pragma unroll
  for (int l = 0; l < 4; ++l) {
    const int g = (l * 8 + w) * 64 + lane; /* granule id 0..2047 */
    const int r = g >> 3;                  /* tile row 0..255 */
    const int cg = (g & 7) ^ (r & 7);      /* pre-swizzled source granule */
    aoff[l] = (row0 + r) * DIM + cg * 8;
    boff[l] = r * DIM + cg * 8;
    loff[l] = (l * 8 + w) * 512;
  }

  auto stage = [&](short* Ad, short* Bd, int gk) {
    if (gk >= NGK) gk = NGK - 2; /* tail: idempotent re-stage of dead buffer */
    const int d0 = (gk & 7) * BKG;
    const size_t cb0 = (size_t)(seg0 + (gk >> 3) * BNG) * DIM;
#pragma unroll
    for (int l = 0; l < 4; ++l) {
      GLDS16(znb + (size_t)aoff[l] + d0, Ad + loff[l]);
      GLDS16(cnb + cb0 + boff[l] + d0, Bd + loff[l]);
    }
  };

  floatx4 acc[8][4];
#pragma unroll
  for (int i = 0; i < 8; ++i)
#pragma unroll
    for (int n = 0; n < 4; ++n) {
      floatx4 zz = {0.f, 0.f, 0.f, 0.f};
      acc[i][n] = zz;
    }

  /* full K-tile compute: 8 bf reads + 16 af reads + 64 MFMA, no barriers */
  auto compute = [&](const short* Ac, const short* Bc) {
    short8 bfr[4][2];
#pragma unroll
    for (int n = 0; n < 4; ++n)
#pragma unroll
      for (int k2 = 0; k2 < 2; ++k2) {
        const int rb = wc * 64 + n * 16 + l15;
        bfr[n][k2] =
            *(const short8*)&Bc[rb * 64 + (((l4 + k2 * 4) ^ (rb & 7)) << 3)];
      }
#pragma unroll
    for (int i = 0; i < 8; ++i) {
      short8 af[2];
#pragma unroll
      for (int k2 = 0; k2 < 2; ++k2) {
        const int ra = wr * 128 + i * 16 + l15;
        af[k2] =
            *(const short8*)&Ac[ra * 64 + (((l4 + k2 * 4) ^ (ra & 7)) << 3)];
      }
#pragma unroll
      for (int n = 0; n < 4; ++n)
#pragma unroll
        for (int k2 = 0; k2 < 2; ++k2)
          acc[i][n] = __builtin_amdgcn_mfma_f32_16x16x32_bf16(
              af[k2], bfr[n][k2], acc[i][n], 0, 0, 0);
    }
  };

  auto epilogue = [&](int col0) {
    /* step A: wave-local per-row max over this wave's 64 cols */
#pragma unroll
    for (int i = 0; i < 8; ++i)
#pragma unroll
      for (int r = 0; r < 4; ++r) {
        float v = fmaxf(fmaxf(acc[i][0][r], acc[i][1][r]),
                        fmaxf(acc[i][2][r], acc[i][3][r]));
#pragma unroll
        for (int off = 1; off < 16; off <<= 1)
          v = fmaxf(v, __shfl_xor(v, off, 64));
        if (l15 == 0) redm[wr * 128 + i * 16 + l4 * 4 + r][wc] = v;
      }
    __syncthreads();
    /* step B1: flat, one lane per row: fold 4 wave-maxes, global atomicMax,
       publish threshold value to thbuf */
    if (lane < 32) {
      const int rr = w * 32 + (lane & 31);
      const float4 m4 = *(const float4*)redm[rr];
      const float nm = fmaxf(fmaxf(m4.x, m4.y), fmaxf(m4.z, m4.w));
      const unsigned key = fkey(nm);
      const unsigned old = atomicMax(&gmax[row0 + rr], key);
      thbuf[rr] = fkey_inv(old > key ? old : key);
    }
    __syncthreads();
    /* step B2: threshold + collect from thbuf */
#pragma unroll
    for (int i = 0; i < 8; ++i)
#pragma unroll
      for (int r = 0; r < 4; ++r) {
        const int rowt = wr * 128 + i * 16 + l4 * 4 + r;
        const float th = thbuf[rowt] - TAU;
        const int rowg = row0 + rowt;
#pragma unroll
        for (int n = 0; n < 4; ++n) {
          if (acc[i][n][r] >= th) {
            const int slot = atomicAdd(&counts[rowg], 1);
            if (slot < MAXC)
              cands[rowg * MAXC + slot] = col0 + wc * 64 + n * 16 + l15;
          }
        }
#pragma unroll
        for (int n = 0; n < 4; ++n) acc[i][n][r] = 0.f;
      }
    __syncthreads();
  };

  /* prologue: K-tile 0 into As0/Bs0 */
  stage(As0, Bs0, 0);

  for (int gk = 0; gk < NGK; gk += 2) {
    /* publish even tile; immediately issue odd tile's stage */
    asm volatile("s_waitcnt vmcnt(0)" ::: "memory");
    __builtin_amdgcn_s_barrier();
    stage(As1, Bs1, gk + 1);
    compute(As0, Bs0);

    /* publish odd tile; immediately issue next even tile's stage */
    asm volatile("s_waitcnt vmcnt(0)" ::: "memory");
    __builtin_amdgcn_s_barrier();
    stage(As0, Bs0, gk + 2);
    compute(As1, Bs1);

    /* col-tile boundary: (gk+1)&7 == 7  <=>  gk&7 == 6 */
    if ((gk & 7) == 6) epilogue(seg0 + (gk >> 3) * BNG);
  }
}

// ---------------------------------------------------------------------------
// fp32-EMULATED rescore + fused output. cnt==1 -> the single candidate IS the
// bf16 argmax with no rival in the TAU band -> exact argmax by the same
// premise the filter already relies on; skip the dot entirely. Output phase
// reads zn from LDS (bits == __fdiv_rn(z,n), identical to old k_output).
// ---------------------------------------------------------------------------
__global__ __launch_bounds__(256) void k_rescore_out(
    const float* __restrict__ z, const float* __restrict__ normz,
    const float* __restrict__ cnf, const int* __restrict__ counts,
    const int* __restrict__ cands, float* __restrict__ out,
    float* __restrict__ lossacc) {
  __shared__ __align__(16) float zn[4][DIM];
  const int wv = threadIdx.x >> 6;
  const int lane = threadIdx.x & 63;
  const int row = blockIdx.x * 4 + wv;
  const float n = normz[row];
  const float* zr = z + (size_t)row * DIM;
#pragma unroll
  for (int j = 0; j < 8; ++j) {
    const int d = lane * 8 + j;
    zn[wv][d] = __fdiv_rn(zr[d], n);
  }
  __syncthreads();
  const int cnt = counts[row];
  int bk;
  if (cnt == 1) {
    bk = cands[row * MAXC] & (KCODES - 1);
  } else {
    const bool fullscan = (cnt <= 0) || (cnt > MAXC);
    ull best = 0ull;
    if (!fullscan) {
      const int idx = (lane < cnt) ? lane : (cnt - 1);
      const int k = cands[row * MAXC + idx] & (KCODES - 1);
      const float* cr = cnf + (size_t)k * DIM;
      float a1 = 0.f, a2 = 0.f;
      for (int d = 0; d < CHAINSPLIT; d += 4) {
        const float4 c = *(const float4*)(cr + d);
        a1 = fmaf(zn[wv][d], c.x, a1);
        a1 = fmaf(zn[wv][d + 1], c.y, a1);
        a1 = fmaf(zn[wv][d + 2], c.z, a1);
        a1 = fmaf(zn[wv][d + 3], c.w, a1);
      }
      for (int d = CHAINSPLIT; d < DIM; d += 4) {
        const float4 c = *(const float4*)(cr + d);
        a2 = fmaf(zn[wv][d], c.x, a2);
        a2 = fmaf(zn[wv][d + 1], c.y, a2);
        a2 = fmaf(zn[wv][d + 2], c.z, a2);
        a2 = fmaf(zn[wv][d + 3], c.w, a2);
      }
      const float s = __fadd_rn(a1, a2);
      if (lane < cnt) best = ((ull)fkey(s) << 32) | (ull)(8191 - k);
    } else {
      for (int base = 0; base < KCODES; base += 64) {
        const int k = base + lane;
        const float* cr = cnf + (size_t)k * DIM;
        float a1 = 0.f, a2 = 0.f;
        for (int d = 0; d < CHAINSPLIT; d += 4) {
          const float4 c = *(const float4*)(cr + d);
          a1 = fmaf(zn[wv][d], c.x, a1);
          a1 = fmaf(zn[wv][d + 1], c.y, a1);
          a1 = fmaf(zn[wv][d + 2], c.z, a1);
          a1 = fmaf(zn[wv][d + 3], c.w, a1);
        }
        for (int d = CHAINSPLIT; d < DIM; d += 4) {
          const float4 c = *(const float4*)(cr + d);
          a2 = fmaf(zn[wv][d], c.x, a2);
          a2 = fmaf(zn[wv][d + 1], c.y, a2);
          a2 = fmaf(zn[wv][d + 2], c.z, a2);
          a2 = fmaf(zn[wv][d + 3], c.w, a2);
        }
        const float s = __fadd_rn(a1, a2);
        const ull q = ((ull)fkey(s) << 32) | (ull)(8191 - k);
        best = (q > best) ? q : best;
      }
    }
#pragma unroll
    for (int off = 1; off < 64; off <<= 1) {
      const ull o = __shfl_xor(best, off, 64);
      best = (o > best) ? o : best;
    }
    bk = 8191 - (int)(best & 0xFFFFFFFFull);
  }

  /* ---- fused output: zq rows, index, loss (bit-identical to k_output) */
  const float4* cr4 = (const float4*)(cnf + (size_t)bk * DIM);
  const float4* znr = (const float4*)zn[wv];
  float ss = 0.0f;
  float4* orow = (float4*)(out + (size_t)row * DIM);
#pragma unroll
  for (int h = 0; h < 2; ++h) {
    const float4 q = cr4[lane + 64 * h];
    const float4 zv = znr[lane + 64 * h];
    orow[lane + 64 * h] = q;
    const float d0 = q.x - zv.x;
    const float d1 = q.y - zv.y;
    const float d2 = q.z - zv.z;
    const float d3 = q.w - zv.w;
    ss += d0 * d0 + d1 * d1 + d2 * d2 + d3 * d3;
  }
#pragma unroll
  for (int off = 1; off < 64; off <<= 1) ss += __shfl_xor(ss, off, 64);
  if (lane == 0) {
    atomicAdd(lossacc, ss);
    out[(size_t)NROWS * DIM + row] = (float)bk;
  }
}

__global__ void k_loss_final(const float* __restrict__ lossacc,
                             float* __restrict__ out) {
  if (threadIdx.x == 0 && blockIdx.x == 0)
    out[(size_t)NROWS * DIM + NROWS] =
        1.5f * (*lossacc) / (float)((size_t)NROWS * DIM);
}

// ---------------------------------------------------------------------------
extern "C" void kernel_launch(void* const* d_in, const int* in_sizes, int n_in,
                              void* d_out, int out_size, void* d_ws, size_t ws_size,
                              hipStream_t stream) {
  const float* z = (const float*)d_in[0];
  const float* cb = (const float*)d_in[1];
  char* ws = (char*)d_ws;
  // workspace layout (~67.6 MB total)
  float* normz = (float*)(ws);                             // 131072
  float* normc = (float*)(ws + 131072);                    // 32768
  int* counts = (int*)(ws + 163840);                       // 131072
  unsigned* gmax = (unsigned*)(ws + 294912);               // 131072
  float* lossacc = (float*)(ws + 425984);                  // 4 (padded)
  int* cands = (int*)(ws + 458752);                        // 8388608
  unsigned short* znb = (unsigned short*)(ws + 8847360);   // 33554432
  unsigned short* cnb = (unsigned short*)(ws + 42401792);  // 8388608
  float* cnf = (float*)(ws + 50790400);                    // 16777216
  float* out = (float*)d_out;

  k_rownorm2<<<dim3(NROWS / 32 + KCODES / 32), dim3(256), 0, stream>>>(
      z, cb, normz, normc, counts, gmax, lossacc);
  k_normstore2<<<dim3(NROWS / 4 + KCODES / 4), dim3(256), 0, stream>>>(
      z, cb, normz, normc, znb, cnb, cnf);
  k_gemm_collect<<<dim3(NROWS / BMG, KSPLIT), dim3(512), 0, stream>>>(
      znb, cnb, counts, cands, gmax);
  k_rescore_out<<<dim3(NROWS / 4), dim3(256), 0, stream>>>(
      z, normz, cnf, counts, cands, out, lossacc);
  k_loss_final<<<dim3(1), dim3(64), 0, stream>>>(lossacc, out);
}

// Round 6
// 716.771 us; speedup vs baseline: 1.7089x; 1.3972x over previous
//
#include <hip/hip_runtime.h>
#include <stdint.h>
#include <stddef.h>

#define NROWS 32768
#define KCODES 8192
#define DIM 512

/* ---- filter GEMM: R5 core (8 waves, 256^2 tile, 1 drain per K-tile) ---- */
#define BMG 256
#define BNG 256
#define BKG 64
#define KSPLIT 2
#define SEGC (KCODES / KSPLIT)          /* 4096 */
#define NGK ((SEGC / BNG) * (DIM / BKG)) /* 128 K-tiles per block */
#define TAU 1.5e-3f
#define MAXC 64
#define CHAINSPLIT 384 /* OpenBLAS sgemm kc */

typedef __attribute__((ext_vector_type(8))) short short8;
typedef __attribute__((ext_vector_type(4))) float floatx4;
typedef unsigned long long ull;

static __device__ __forceinline__ unsigned short f2bf(float f) {
  unsigned u = __float_as_uint(f);
  unsigned r = (u + 0x7FFFu + ((u >> 16) & 1u)) >> 16;
  return (unsigned short)r;
}
// monotone float->uint key (order-preserving for finite floats)
static __device__ __forceinline__ unsigned fkey(float s) {
  unsigned b = __float_as_uint(s);
  return b ^ (((int)b < 0) ? 0xFFFFFFFFu : 0x80000000u);
}
static __device__ __forceinline__ float fkey_inv(unsigned u) {
  return __uint_as_float((u & 0x80000000u) ? (u ^ 0x80000000u) : ~u);
}

#define GLDS16(g, l)                                                        \
  __builtin_amdgcn_global_load_lds(                                         \
      (const __attribute__((address_space(1))) unsigned int*)(g),           \
      (__attribute__((address_space(3))) unsigned int*)(l), 16, 0, 0)

// ---------------------------------------------------------------------------
// FUSED numpy-exact row norm + normalize + store. One wave per row; the row
// is loaded ONCE (float4 x2 per lane, kept in registers), mirrored to LDS so
// lanes 0..31 can run the validated strided accumulator chains:
//   lane (b*8+j), b=0..3, j=0..7: r = p[b*128+j]^2 then 15 sequential
//   __fadd_rn(__fmul_rn) terms at stride 8  -> identical term order to the
//   previous k_rownorm2.  Tree combine: __shfl_xor(1,2,4) within the 8-lane
//   group (same adjacency as before), then blocks combined pairwise
//   ((b0+b1)+(b2+b3)) on lane 0 -- bit-identical to the validated kernel.
// Division + bf16/f32 stores identical to k_normstore2. Also zero-inits
// counts/gmax for z rows (taking over from the removed k_rownorm2).
// ---------------------------------------------------------------------------
__global__ __launch_bounds__(256) void k_normfused(
    const float* __restrict__ z, const float* __restrict__ cb,
    float* __restrict__ normz, float* __restrict__ normc,
    unsigned short* __restrict__ znb, unsigned short* __restrict__ cnb,
    float* __restrict__ cnf, int* __restrict__ counts,
    unsigned* __restrict__ gmax) {
  __shared__ __align__(16) float rowbuf[4][DIM];
  const int wv = threadIdx.x >> 6;
  const int lane = threadIdx.x & 63;
  const int b = blockIdx.x;
  const bool isz = (b < NROWS / 4);
  const int row = (isz ? b : (b - NROWS / 4)) * 4 + wv;
  const float* x = isz ? z : cb;
  if (isz && lane == 0) {
    counts[row] = 0;
    gmax[row] = 0u; /* decodes below any fkey(score) */
  }
  const float4* xr = (const float4*)(x + (size_t)row * DIM);
  const float4 v0 = xr[lane];      /* floats 4*lane   .. 4*lane+3   */
  const float4 v1 = xr[lane + 64]; /* floats 256+4*lane .. +3       */
  ((float4*)rowbuf[wv])[lane] = v0;
  ((float4*)rowbuf[wv])[lane + 64] = v1;
  __syncthreads();

  float tot = 0.0f;
  if (lane < 32) {
    const int bb = lane >> 3;
    const int j = lane & 7;
    const float* rb = rowbuf[wv] + bb * 128;
    float r = __fmul_rn(rb[j], rb[j]);
    for (int i = 8; i < 128; i += 8) {
      const float t = rb[i + j];
      r = __fadd_rn(r, __fmul_rn(t, t));
    }
    r = __fadd_rn(r, __shfl_xor(r, 1, 64));
    r = __fadd_rn(r, __shfl_xor(r, 2, 64));
    r = __fadd_rn(r, __shfl_xor(r, 4, 64));
    /* lanes 0..7 hold blk0, 8..15 blk1, 16..23 blk2, 24..31 blk3 */
    const float r1 = __shfl(r, 8, 64);
    const float r2 = __shfl(r, 16, 64);
    const float r3 = __shfl(r, 24, 64);
    tot = __fadd_rn(__fadd_rn(r, r1), __fadd_rn(r2, r3)); /* valid on lane 0 */
  }
  tot = __shfl(tot, 0, 64);
  const float n = fmaxf(__fsqrt_rn(tot), 1e-12f);
  if (lane == 0) (isz ? normz : normc)[row] = n;

  unsigned short* xb = isz ? znb : cnb;
  {
    const float q0 = __fdiv_rn(v0.x, n);
    const float q1 = __fdiv_rn(v0.y, n);
    const float q2 = __fdiv_rn(v0.z, n);
    const float q3 = __fdiv_rn(v0.w, n);
    if (!isz)
      ((float4*)(cnf + (size_t)row * DIM))[lane] = make_float4(q0, q1, q2, q3);
    *(ushort4*)(xb + (size_t)row * DIM + 4 * lane) =
        make_ushort4(f2bf(q0), f2bf(q1), f2bf(q2), f2bf(q3));
  }
  {
    const float q0 = __fdiv_rn(v1.x, n);
    const float q1 = __fdiv_rn(v1.y, n);
    const float q2 = __fdiv_rn(v1.z, n);
    const float q3 = __fdiv_rn(v1.w, n);
    if (!isz)
      ((float4*)(cnf + (size_t)row * DIM))[lane + 64] =
          make_float4(q0, q1, q2, q3);
    *(ushort4*)(xb + (size_t)row * DIM + 256 + 4 * lane) =
        make_ushort4(f2bf(q0), f2bf(q1), f2bf(q2), f2bf(q3));
  }
}

// ---------------------------------------------------------------------------
// bf16 MFMA filter GEMM: EXACT R5 kernel (measured 447us) -- 8 waves
// (2M x 4N, wave tile 128x64), 256x256 tile, double-buffered LDS, one
// vmcnt(0) drain + barrier per BK=64 K-tile, stage of tile t+1 issued right
// after the barrier publishing tile t. Collect epilogue: flat global
// atomicMax (gmax, monotone key space) -> thbuf thresholds -> band collect.
// UNCHANGED this round (A/B control for the tail changes).
// ---------------------------------------------------------------------------
__global__ __launch_bounds__(512, 2) void k_gemm_collect(
    const unsigned short* __restrict__ znb, const unsigned short* __restrict__ cnb,
    int* __restrict__ counts, int* __restrict__ cands,
    unsigned* __restrict__ gmax) {
  __shared__ __align__(16) short As0[BMG * BKG]; /* 32KB */
  __shared__ __align__(16) short Bs0[BNG * BKG]; /* 32KB */
  __shared__ __align__(16) short As1[BMG * BKG]; /* 32KB */
  __shared__ __align__(16) short Bs1[BNG * BKG]; /* 32KB */
  __shared__ __align__(16) float redm[256][4];
  __shared__ float thbuf[256];

  const int tid = threadIdx.x;
  const int lane = tid & 63;
  const int w = tid >> 6; /* wave 0..7 */
  const int wr = w >> 2;  /* M half: rows wr*128.. */
  const int wc = w & 3;   /* N quarter: cols wc*64.. */
  const int l15 = lane & 15;
  const int l4 = lane >> 4;

  /* XCD-aware bijective swizzle: 256 blocks -> 32 contiguous per XCD */
  const int bid = blockIdx.y * (NROWS / BMG) + blockIdx.x;
  const int logical = (bid & 7) * 32 + (bid >> 3);
  const int row0 = (logical & (NROWS / BMG - 1)) * BMG;
  const int seg0 = (logical >> 7) * SEGC;

  /* per-lane loop-invariant staging geometry (shorts) */
  int aoff[4], boff[4], loff[4];
#pragma unroll
  for (int l = 0; l < 4; ++l) {
    const int g = (l * 8 + w) * 64 + lane; /* granule id 0..2047 */
    const int r = g >> 3;                  /* tile row 0..255 */
    const int cg = (g & 7) ^ (r & 7);      /* pre-swizzled source granule */
    aoff[l] = (row0 + r) * DIM + cg * 8;
    boff[l] = r * DIM + cg * 8;
    loff[l] = (l * 8 + w) * 512;
  }

  auto stage = [&](short* Ad, short* Bd, int gk) {
    if (gk >= NGK) gk = NGK - 2; /* tail: idempotent re-stage of dead buffer */
    const int d0 = (gk & 7) * BKG;
    const size_t cb0 = (size_t)(seg0 + (gk >> 3) * BNG) * DIM;
#pragma unroll
    for (int l = 0; l < 4; ++l) {
      GLDS16(znb + (size_t)aoff[l] + d0, Ad + loff[l]);
      GLDS16(cnb + cb0 + boff[l] + d0, Bd + loff[l]);
    }
  };

  floatx4 acc[8][4];
#pragma unroll
  for (int i = 0; i < 8; ++i)
#pragma unroll
    for (int n = 0; n < 4; ++n) {
      floatx4 zz = {0.f, 0.f, 0.f, 0.f};
      acc[i][n] = zz;
    }

  /* full K-tile compute: 8 bf reads + 16 af reads + 64 MFMA, no barriers */
  auto compute = [&](const short* Ac, const short* Bc) {
    short8 bfr[4][2];
#pragma unroll
    for (int n = 0; n < 4; ++n)
#pragma unroll
      for (int k2 = 0; k2 < 2; ++k2) {
        const int rb = wc * 64 + n * 16 + l15;
        bfr[n][k2] =
            *(const short8*)&Bc[rb * 64 + (((l4 + k2 * 4) ^ (rb & 7)) << 3)];
      }
#pragma unroll
    for (int i = 0; i < 8; ++i) {
      short8 af[2];
#pragma unroll
      for (int k2 = 0; k2 < 2; ++k2) {
        const int ra = wr * 128 + i * 16 + l15;
        af[k2] =
            *(const short8*)&Ac[ra * 64 + (((l4 + k2 * 4) ^ (ra & 7)) << 3)];
      }
#pragma unroll
      for (int n = 0; n < 4; ++n)
#pragma unroll
        for (int k2 = 0; k2 < 2; ++k2)
          acc[i][n] = __builtin_amdgcn_mfma_f32_16x16x32_bf16(
              af[k2], bfr[n][k2], acc[i][n], 0, 0, 0);
    }
  };

  auto epilogue = [&](int col0) {
    /* step A: wave-local per-row max over this wave's 64 cols */
#pragma unroll
    for (int i = 0; i < 8; ++i)
#pragma unroll
      for (int r = 0; r < 4; ++r) {
        float v = fmaxf(fmaxf(acc[i][0][r], acc[i][1][r]),
                        fmaxf(acc[i][2][r], acc[i][3][r]));
#pragma unroll
        for (int off = 1; off < 16; off <<= 1)
          v = fmaxf(v, __shfl_xor(v, off, 64));
        if (l15 == 0) redm[wr * 128 + i * 16 + l4 * 4 + r][wc] = v;
      }
    __syncthreads();
    /* step B1: flat, one lane per row: fold 4 wave-maxes, global atomicMax,
       publish threshold value to thbuf */
    if (lane < 32) {
      const int rr = w * 32 + (lane & 31);
      const float4 m4 = *(const float4*)redm[rr];
      const float nm = fmaxf(fmaxf(m4.x, m4.y), fmaxf(m4.z, m4.w));
      const unsigned key = fkey(nm);
      const unsigned old = atomicMax(&gmax[row0 + rr], key);
      thbuf[rr] = fkey_inv(old > key ? old : key);
    }
    __syncthreads();
    /* step B2: threshold + collect from thbuf */
#pragma unroll
    for (int i = 0; i < 8; ++i)
#pragma unroll
      for (int r = 0; r < 4; ++r) {
        const int rowt = wr * 128 + i * 16 + l4 * 4 + r;
        const float th = thbuf[rowt] - TAU;
        const int rowg = row0 + rowt;
#pragma unroll
        for (int n = 0; n < 4; ++n) {
          if (acc[i][n][r] >= th) {
            const int slot = atomicAdd(&counts[rowg], 1);
            if (slot < MAXC)
              cands[rowg * MAXC + slot] = col0 + wc * 64 + n * 16 + l15;
          }
        }
#pragma unroll
        for (int n = 0; n < 4; ++n) acc[i][n][r] = 0.f;
      }
    __syncthreads();
  };

  /* prologue: K-tile 0 into As0/Bs0 */
  stage(As0, Bs0, 0);

  for (int gk = 0; gk < NGK; gk += 2) {
    /* publish even tile; immediately issue odd tile's stage */
    asm volatile("s_waitcnt vmcnt(0)" ::: "memory");
    __builtin_amdgcn_s_barrier();
    stage(As1, Bs1, gk + 1);
    compute(As0, Bs0);

    /* publish odd tile; immediately issue next even tile's stage */
    asm volatile("s_waitcnt vmcnt(0)" ::: "memory");
    __builtin_amdgcn_s_barrier();
    stage(As0, Bs0, gk + 2);
    compute(As1, Bs1);

    /* col-tile boundary: (gk+1)&7 == 7  <=>  gk&7 == 6 */
    if ((gk & 7) == 6) epilogue(seg0 + (gk >> 3) * BNG);
  }
}

// ---------------------------------------------------------------------------
// fp32-EMULATED rescore + fused output. cnt==1 -> the single candidate IS the
// bf16 argmax (no rival in the TAU band) -> index copy. Loss now accumulates
// into a per-block partial (lossparts[blockIdx]) via LDS reduce -- NO global
// atomics (the 32768 same-address atomicAdds were a serialization hot-spot).
// ---------------------------------------------------------------------------
__global__ __launch_bounds__(256) void k_rescore_out(
    const float* __restrict__ z, const float* __restrict__ normz,
    const float* __restrict__ cnf, const int* __restrict__ counts,
    const int* __restrict__ cands, float* __restrict__ out,
    float* __restrict__ lossparts) {
  __shared__ __align__(16) float zn[4][DIM];
  __shared__ float lred[4];
  const int wv = threadIdx.x >> 6;
  const int lane = threadIdx.x & 63;
  const int row = blockIdx.x * 4 + wv;
  const float n = normz[row];
  const float* zr = z + (size_t)row * DIM;
#pragma unroll
  for (int j = 0; j < 8; ++j) {
    const int d = lane * 8 + j;
    zn[wv][d] = __fdiv_rn(zr[d], n);
  }
  __syncthreads();
  const int cnt = counts[row];
  int bk;
  if (cnt == 1) {
    bk = cands[row * MAXC] & (KCODES - 1);
  } else {
    const bool fullscan = (cnt <= 0) || (cnt > MAXC);
    ull best = 0ull;
    if (!fullscan) {
      const int idx = (lane < cnt) ? lane : (cnt - 1);
      const int k = cands[row * MAXC + idx] & (KCODES - 1);
      const float* cr = cnf + (size_t)k * DIM;
      float a1 = 0.f, a2 = 0.f;
      for (int d = 0; d < CHAINSPLIT; d += 4) {
        const float4 c = *(const float4*)(cr + d);
        a1 = fmaf(zn[wv][d], c.x, a1);
        a1 = fmaf(zn[wv][d + 1], c.y, a1);
        a1 = fmaf(zn[wv][d + 2], c.z, a1);
        a1 = fmaf(zn[wv][d + 3], c.w, a1);
      }
      for (int d = CHAINSPLIT; d < DIM; d += 4) {
        const float4 c = *(const float4*)(cr + d);
        a2 = fmaf(zn[wv][d], c.x, a2);
        a2 = fmaf(zn[wv][d + 1], c.y, a2);
        a2 = fmaf(zn[wv][d + 2], c.z, a2);
        a2 = fmaf(zn[wv][d + 3], c.w, a2);
      }
      const float s = __fadd_rn(a1, a2);
      if (lane < cnt) best = ((ull)fkey(s) << 32) | (ull)(8191 - k);
    } else {
      for (int base = 0; base < KCODES; base += 64) {
        const int k = base + lane;
        const float* cr = cnf + (size_t)k * DIM;
        float a1 = 0.f, a2 = 0.f;
        for (int d = 0; d < CHAINSPLIT; d += 4) {
          const float4 c = *(const float4*)(cr + d);
          a1 = fmaf(zn[wv][d], c.x, a1);
          a1 = fmaf(zn[wv][d + 1], c.y, a1);
          a1 = fmaf(zn[wv][d + 2], c.z, a1);
          a1 = fmaf(zn[wv][d + 3], c.w, a1);
        }
        for (int d = CHAINSPLIT; d < DIM; d += 4) {
          const float4 c = *(const float4*)(cr + d);
          a2 = fmaf(zn[wv][d], c.x, a2);
          a2 = fmaf(zn[wv][d + 1], c.y, a2);
          a2 = fmaf(zn[wv][d + 2], c.z, a2);
          a2 = fmaf(zn[wv][d + 3], c.w, a2);
        }
        const float s = __fadd_rn(a1, a2);
        const ull q = ((ull)fkey(s) << 32) | (ull)(8191 - k);
        best = (q > best) ? q : best;
      }
    }
#pragma unroll
    for (int off = 1; off < 64; off <<= 1) {
      const ull o = __shfl_xor(best, off, 64);
      best = (o > best) ? o : best;
    }
    bk = 8191 - (int)(best & 0xFFFFFFFFull);
  }

  /* ---- fused output: zq rows, index, per-block loss partial */
  const float4* cr4 = (const float4*)(cnf + (size_t)bk * DIM);
  const float4* znr = (const float4*)zn[wv];
  float ss = 0.0f;
  float4* orow = (float4*)(out + (size_t)row * DIM);
#pragma unroll
  for (int h = 0; h < 2; ++h) {
    const float4 q = cr4[lane + 64 * h];
    const float4 zv = znr[lane + 64 * h];
    orow[lane + 64 * h] = q;
    const float d0 = q.x - zv.x;
    const float d1 = q.y - zv.y;
    const float d2 = q.z - zv.z;
    const float d3 = q.w - zv.w;
    ss += d0 * d0 + d1 * d1 + d2 * d2 + d3 * d3;
  }
#pragma unroll
  for (int off = 1; off < 64; off <<= 1) ss += __shfl_xor(ss, off, 64);
  if (lane == 0) {
    lred[wv] = ss;
    out[(size_t)NROWS * DIM + row] = (float)bk;
  }
  __syncthreads();
  if (threadIdx.x == 0)
    lossparts[blockIdx.x] =
        __fadd_rn(__fadd_rn(lred[0], lred[1]), __fadd_rn(lred[2], lred[3]));
}

// ---------------------------------------------------------------------------
// Deterministic final loss reduction over 8192 per-block partials.
// ---------------------------------------------------------------------------
__global__ __launch_bounds__(256) void k_loss_final(
    const float* __restrict__ lossparts, float* __restrict__ out) {
  __shared__ float sb[256];
  float s = 0.0f;
  for (int i = threadIdx.x; i < NROWS / 4; i += 256) s += lossparts[i];
  sb[threadIdx.x] = s;
  __syncthreads();
  for (int off = 128; off > 0; off >>= 1) {
    if (threadIdx.x < off) sb[threadIdx.x] += sb[threadIdx.x + off];
    __syncthreads();
  }
  if (threadIdx.x == 0)
    out[(size_t)NROWS * DIM + NROWS] =
        1.5f * sb[0] / (float)((size_t)NROWS * DIM);
}

// ---------------------------------------------------------------------------
extern "C" void kernel_launch(void* const* d_in, const int* in_sizes, int n_in,
                              void* d_out, int out_size, void* d_ws, size_t ws_size,
                              hipStream_t stream) {
  const float* z = (const float*)d_in[0];
  const float* cb = (const float*)d_in[1];
  char* ws = (char*)d_ws;
  // workspace layout (~67.6 MB total)
  float* normz = (float*)(ws);                             // 131072
  float* normc = (float*)(ws + 131072);                    // 32768
  int* counts = (int*)(ws + 163840);                       // 131072
  unsigned* gmax = (unsigned*)(ws + 294912);               // 131072
  float* lossparts = (float*)(ws + 425984);                // 32768 (8192 f32)
  int* cands = (int*)(ws + 458752);                        // 8388608
  unsigned short* znb = (unsigned short*)(ws + 8847360);   // 33554432
  unsigned short* cnb = (unsigned short*)(ws + 42401792);  // 8388608
  float* cnf = (float*)(ws + 50790400);                    // 16777216
  float* out = (float*)d_out;

  k_normfused<<<dim3(NROWS / 4 + KCODES / 4), dim3(256), 0, stream>>>(
      z, cb, normz, normc, znb, cnb, cnf, counts, gmax);
  k_gemm_collect<<<dim3(NROWS / BMG, KSPLIT), dim3(512), 0, stream>>>(
      znb, cnb, counts, cands, gmax);
  k_rescore_out<<<dim3(NROWS / 4), dim3(256), 0, stream>>>(
      z, normz, cnf, counts, cands, out, lossparts);
  k_loss_final<<<dim3(1), dim3(256), 0, stream>>>(lossparts, out);
}